// Round 2
// baseline (2135.050 us; speedup 1.0000x reference)
//
#include <hip/hip_runtime.h>
#include <hip/hip_bf16.h>
#include <math.h>

// Problem constants (B,T,C,H) = (4, 2048, 1024, 16), D = 64.
#define B_   4
#define T_   2048
#define C_   1024
#define H_   16
#define D_   64
#define TC3  3072   // 3*C

// ---------------------------------------------------------------------------
// GEMM: C[M,N] = A[M,K] @ Bm[K,N] + bias[N]   (unchanged from R1 baseline)
// ---------------------------------------------------------------------------
__global__ __launch_bounds__(256)
void sgemm_bias(const float* __restrict__ A, const float* __restrict__ Bm,
                const float* __restrict__ bias, float* __restrict__ Cm,
                int M, int N, int K, int lda) {
  __shared__ __align__(16) float As[8][128];   // transposed: As[k][m]
  __shared__ __align__(16) float Bs[8][128];

  const int tid  = threadIdx.x;
  const int tr   = tid >> 4;
  const int tc   = tid & 15;
  const int row0 = blockIdx.y * 128;
  const int col0 = blockIdx.x * 128;

  const int arow = tid >> 1;
  const int acol = (tid & 1) * 4;
  const int brow = tid >> 5;
  const int bcol = (tid & 31) * 4;

  const float* Aptr = A  + (size_t)(row0 + arow) * lda + acol;
  const float* Bptr = Bm + (size_t)brow * N + col0 + bcol;

  float acc[8][8];
#pragma unroll
  for (int i = 0; i < 8; ++i)
#pragma unroll
    for (int j = 0; j < 8; ++j) acc[i][j] = 0.f;

  for (int kt = 0; kt < K; kt += 8) {
    float4 av = *(const float4*)(Aptr + kt);
    float4 bv = *(const float4*)(Bptr + (size_t)kt * N);
    As[acol + 0][arow] = av.x;
    As[acol + 1][arow] = av.y;
    As[acol + 2][arow] = av.z;
    As[acol + 3][arow] = av.w;
    *(float4*)&Bs[brow][bcol] = bv;
    __syncthreads();

#pragma unroll
    for (int k = 0; k < 8; ++k) {
      float4 a0 = *(const float4*)&As[k][tr * 8];
      float4 a1 = *(const float4*)&As[k][tr * 8 + 4];
      float4 b0 = *(const float4*)&Bs[k][tc * 8];
      float4 b1 = *(const float4*)&Bs[k][tc * 8 + 4];
      float af[8] = {a0.x, a0.y, a0.z, a0.w, a1.x, a1.y, a1.z, a1.w};
      float bf[8] = {b0.x, b0.y, b0.z, b0.w, b1.x, b1.y, b1.z, b1.w};
#pragma unroll
      for (int i = 0; i < 8; ++i)
#pragma unroll
        for (int j = 0; j < 8; ++j)
          acc[i][j] = fmaf(af[i], bf[j], acc[i][j]);
    }
    __syncthreads();
  }

  float4 bs0 = *(const float4*)&bias[col0 + tc * 8];
  float4 bs1 = *(const float4*)&bias[col0 + tc * 8 + 4];
  float bf[8] = {bs0.x, bs0.y, bs0.z, bs0.w, bs1.x, bs1.y, bs1.z, bs1.w};
#pragma unroll
  for (int i = 0; i < 8; ++i) {
    size_t r = (size_t)(row0 + tr * 8 + i) * N + col0 + tc * 8;
    float4 o0 = {acc[i][0] + bf[0], acc[i][1] + bf[1],
                 acc[i][2] + bf[2], acc[i][3] + bf[3]};
    float4 o1 = {acc[i][4] + bf[4], acc[i][5] + bf[5],
                 acc[i][6] + bf[6], acc[i][7] + bf[7]};
    *(float4*)&Cm[r]     = o0;
    *(float4*)&Cm[r + 4] = o1;
  }
}

// ---------------------------------------------------------------------------
// Fused per-head RMSNorm + RoPE + value output (unchanged).
// ---------------------------------------------------------------------------
__global__ __launch_bounds__(256)
void rmsrope_kernel(float* __restrict__ qkv, const float* __restrict__ lambp,
                    float* __restrict__ valOut) {
  const int unit = blockIdx.x * 4 + (threadIdx.x >> 6);
  const int lane = threadIdx.x & 63;
  const int b = unit / (T_ * H_);
  const int rem = unit % (T_ * H_);
  const int t = rem / H_;
  const int h = rem % H_;
  const size_t base = (size_t)(b * T_ + t) * TC3;
  const float lamb = lambp[0];

  const int i = lane & 31;
  const float inv = 1.0f / powf(10000.0f, (float)(2 * i) * (1.0f / 64.0f));
  const float ang = (float)t * inv;
  const float cs = cosf(ang);
  const float sn = sinf(ang);

  {
    const size_t idx = base + h * 64 + lane;
    float q = qkv[idx];
    float ss = q * q;
    ss += __shfl_xor(ss, 32); ss += __shfl_xor(ss, 16);
    ss += __shfl_xor(ss, 8);  ss += __shfl_xor(ss, 4);
    ss += __shfl_xor(ss, 2);  ss += __shfl_xor(ss, 1);
    float qn = q * (1.0f / sqrtf(ss * (1.0f / 64.0f) + 1e-6f));
    float part = __shfl_xor(qn, 32);
    float out = (lane < 32) ? (qn * cs + part * sn) : (qn * cs - part * sn);
    qkv[idx] = out;
  }
  {
    const size_t idx = base + C_ + h * 64 + lane;
    float k = qkv[idx];
    float ss = k * k;
    ss += __shfl_xor(ss, 32); ss += __shfl_xor(ss, 16);
    ss += __shfl_xor(ss, 8);  ss += __shfl_xor(ss, 4);
    ss += __shfl_xor(ss, 2);  ss += __shfl_xor(ss, 1);
    float kn = k * (1.0f / sqrtf(ss * (1.0f / 64.0f) + 1e-6f));
    float part = __shfl_xor(kn, 32);
    float out = (lane < 32) ? (kn * cs + part * sn) : (kn * cs - part * sn);
    qkv[idx] = out;
  }
  {
    float v = qkv[base + 2 * C_ + h * 64 + lane];
    float val = (1.0f - lamb) * v + lamb * v;
    valOut[(size_t)((b * H_ + h) * T_ + t) * D_ + lane] = val;
  }
}

// ---------------------------------------------------------------------------
// Flash-style causal attention, fp32 — v2.
// Changes vs R1:
//  * XOR-swizzled LDS layout (stride 64, slot = c4 ^ ((r>>2)&7)).
//    Conflict-free on: staging writes, S-loop Q reads (broadcast over 4
//    distinct groups), S-loop K reads (8 groups x 2-way = free per m136),
//    PV-loop P reads (broadcast) and V reads (2-way). Only the 4 P^T-write
//    instrs/wave-iter keep an 8-way conflict (vs 64 conflicted reads in R1).
//  * Global->register prefetch of next K/V tile issued before S-compute,
//    consumed at next staging (hides HBM/L2 latency behind ~4096 FMA cyc).
//  * qt reversed (heavy causal blocks dispatch first -> tail balance).
//  * __expf in softmax (shorter dependent chain).
// LDS: 3 x 16 KB = 48 KB -> 3 blocks/CU. P^T aliases Ks.
// ---------------------------------------------------------------------------
#define SW4(c4, rsh) (((c4) ^ ((rsh) & 7)) * 4)

__global__ __launch_bounds__(256)
void flash_kernel(float* __restrict__ qkv, const float* __restrict__ vvals) {
  __shared__ __align__(16) float Qs[64 * 64];
  __shared__ __align__(16) float Ks[64 * 64];
  __shared__ __align__(16) float Vs[64 * 64];
  float* Ps = Ks;   // P^T overwrites K tile after S-compute

  const int qt = gridDim.x - 1 - blockIdx.x;   // heavy blocks first
  const int h  = blockIdx.y;
  const int b  = blockIdx.z;
  const int tid = threadIdx.x;
  const int ty = tid >> 4;          // 0..15
  const int tx = tid & 15;          // 0..15
  const int q0 = qt * 64;
  const int lrow = tid >> 4;        // 0..15 (load row within 16-row slab)
  const int lc4  = tid & 15;        // column group 0..15

  // Q tile -> LDS (swizzled). First in-loop barrier orders these vs reads.
#pragma unroll
  for (int it = 0; it < 4; ++it) {
    int r = it * 16 + lrow;
    float4 qv = *(const float4*)(
        qkv + (size_t)(b * T_ + q0 + r) * TC3 + h * 64 + lc4 * 4);
    *(float4*)&Qs[r * 64 + SW4(lc4, r >> 2)] = qv;
  }

  // prefetch K/V tile for kt = 0
  float4 kreg[4], vreg[4];
#pragma unroll
  for (int it = 0; it < 4; ++it) {
    int r = it * 16 + lrow;
    kreg[it] = *(const float4*)(
        qkv + (size_t)(b * T_ + r) * TC3 + C_ + h * 64 + lc4 * 4);
    vreg[it] = *(const float4*)(
        vvals + (size_t)((b * H_ + h) * T_ + r) * D_ + lc4 * 4);
  }

  float m_i[4], l_i[4], o[4][4];
#pragma unroll
  for (int ii = 0; ii < 4; ++ii) {
    m_i[ii] = -INFINITY; l_i[ii] = 0.f;
#pragma unroll
    for (int dd = 0; dd < 4; ++dd) o[ii][dd] = 0.f;
  }

  for (int kt = 0; kt <= qt; ++kt) {
    __syncthreads();   // previous Ps(=Ks)/Vs fully consumed
#pragma unroll
    for (int it = 0; it < 4; ++it) {
      int r = it * 16 + lrow;
      *(float4*)&Ks[r * 64 + SW4(lc4, r >> 2)] = kreg[it];
      *(float4*)&Vs[r * 64 + SW4(lc4, r >> 2)] = vreg[it];
    }
    __syncthreads();

    // issue next tile's global loads early (overlap with S-compute)
    if (kt < qt) {
      const int k0n = (kt + 1) * 64;
#pragma unroll
      for (int it = 0; it < 4; ++it) {
        int r = it * 16 + lrow;
        kreg[it] = *(const float4*)(
            qkv + (size_t)(b * T_ + k0n + r) * TC3 + C_ + h * 64 + lc4 * 4);
        vreg[it] = *(const float4*)(
            vvals + (size_t)((b * H_ + h) * T_ + k0n + r) * D_ + lc4 * 4);
      }
    }

    // S = Q K^T  (4x4 per thread, float4 along d, swizzled reads)
    float s[4][4];
#pragma unroll
    for (int ii = 0; ii < 4; ++ii)
#pragma unroll
      for (int jj = 0; jj < 4; ++jj) s[ii][jj] = 0.f;

#pragma unroll 4
    for (int d4 = 0; d4 < 16; ++d4) {
      const int qsl = SW4(d4, ty);   // (4ty+ii)>>2 == ty
      const int ksl = SW4(d4, tx);   // (4tx+jj)>>2 == tx
      float qa[4][4], ka[4][4];
#pragma unroll
      for (int ii = 0; ii < 4; ++ii) {
        float4 qv = *(const float4*)&Qs[(4 * ty + ii) * 64 + qsl];
        qa[ii][0] = qv.x; qa[ii][1] = qv.y; qa[ii][2] = qv.z; qa[ii][3] = qv.w;
      }
#pragma unroll
      for (int jj = 0; jj < 4; ++jj) {
        float4 kv = *(const float4*)&Ks[(4 * tx + jj) * 64 + ksl];
        ka[jj][0] = kv.x; ka[jj][1] = kv.y; ka[jj][2] = kv.z; ka[jj][3] = kv.w;
      }
#pragma unroll
      for (int ii = 0; ii < 4; ++ii)
#pragma unroll
        for (int jj = 0; jj < 4; ++jj)
#pragma unroll
          for (int c = 0; c < 4; ++c)
            s[ii][jj] = fmaf(qa[ii][c], ka[jj][c], s[ii][jj]);
    }

    // scale + causal mask (diagonal tile only)
    const bool diag = (kt == qt);
#pragma unroll
    for (int ii = 0; ii < 4; ++ii)
#pragma unroll
      for (int jj = 0; jj < 4; ++jj) {
        float sv = s[ii][jj] * 0.125f;   // 1/sqrt(64)
        if (diag && (4 * tx + jj > 4 * ty + ii)) sv = -INFINITY;
        s[ii][jj] = sv;
      }

    __syncthreads();   // Ks consumed -> P^T may overwrite

    // online softmax (row state replicated across the 16 tx threads)
    float p[4][4];
#pragma unroll
    for (int ii = 0; ii < 4; ++ii) {
      float rm = fmaxf(fmaxf(s[ii][0], s[ii][1]), fmaxf(s[ii][2], s[ii][3]));
      rm = fmaxf(rm, __shfl_xor(rm, 1));
      rm = fmaxf(rm, __shfl_xor(rm, 2));
      rm = fmaxf(rm, __shfl_xor(rm, 4));
      rm = fmaxf(rm, __shfl_xor(rm, 8));
      float mnew = fmaxf(m_i[ii], rm);
      float alpha = __expf(m_i[ii] - mnew);
      m_i[ii] = mnew;
      float rs = 0.f;
#pragma unroll
      for (int jj = 0; jj < 4; ++jj) {
        p[ii][jj] = __expf(s[ii][jj] - mnew);
        rs += p[ii][jj];
      }
      rs += __shfl_xor(rs, 1); rs += __shfl_xor(rs, 2);
      rs += __shfl_xor(rs, 4); rs += __shfl_xor(rs, 8);
      l_i[ii] = l_i[ii] * alpha + rs;
#pragma unroll
      for (int dd = 0; dd < 4; ++dd) o[ii][dd] *= alpha;
    }

    // write P^T (swizzled); r = 4tx+jj -> rsh = tx
#pragma unroll
    for (int jj = 0; jj < 4; ++jj) {
      float4 pv = {p[0][jj], p[1][jj], p[2][jj], p[3][jj]};
      *(float4*)&Ps[(4 * tx + jj) * 64 + SW4(ty, tx)] = pv;
    }
    __syncthreads();

    // O += P V  (swizzled reads; Ps broadcast, Vs 2-way)
#pragma unroll 4
    for (int j = 0; j < 64; ++j) {
      const int sl = (j >> 2) & 7;
      float4 pv4 = *(const float4*)&Ps[j * 64 + SW4(ty, sl)];
      float4 vv4 = *(const float4*)&Vs[j * 64 + SW4(tx, sl)];
      float pa[4] = {pv4.x, pv4.y, pv4.z, pv4.w};
      float va[4] = {vv4.x, vv4.y, vv4.z, vv4.w};
#pragma unroll
      for (int ii = 0; ii < 4; ++ii)
#pragma unroll
        for (int dd = 0; dd < 4; ++dd)
          o[ii][dd] = fmaf(pa[ii], va[dd], o[ii][dd]);
    }
  }

  // epilogue: O/l into qkv's v-columns, (b, t, h*64+d) layout
#pragma unroll
  for (int ii = 0; ii < 4; ++ii) {
    float invl = 1.0f / l_i[ii];
    int row = q0 + 4 * ty + ii;
    float4 ov = {o[ii][0] * invl, o[ii][1] * invl,
                 o[ii][2] * invl, o[ii][3] * invl};
    *(float4*)&qkv[(size_t)(b * T_ + row) * TC3 + 2 * C_ + h * 64 + 4 * tx] = ov;
  }
}

// ---------------------------------------------------------------------------
// Launch. d_in: x, Wqkv, bqkv, Wproj, bproj, lamb.
// d_out: out (B*T*C) then value (B*H*T*D). ws: qkv (B*T*3C floats).
// ---------------------------------------------------------------------------
extern "C" void kernel_launch(void* const* d_in, const int* in_sizes, int n_in,
                              void* d_out, int out_size, void* d_ws, size_t ws_size,
                              hipStream_t stream) {
  const float* x     = (const float*)d_in[0];
  const float* Wqkv  = (const float*)d_in[1];
  const float* bqkv  = (const float*)d_in[2];
  const float* Wproj = (const float*)d_in[3];
  const float* bproj = (const float*)d_in[4];
  const float* lamb  = (const float*)d_in[5];

  float* out     = (float*)d_out;
  float* val_out = out + (size_t)B_ * T_ * C_;
  float* qkv     = (float*)d_ws;

  sgemm_bias<<<dim3(TC3 / 128, (B_ * T_) / 128), 256, 0, stream>>>(
      x, Wqkv, bqkv, qkv, B_ * T_, TC3, C_, C_);

  rmsrope_kernel<<<dim3((B_ * T_ * H_) / 4), 256, 0, stream>>>(qkv, lamb, val_out);

  flash_kernel<<<dim3(T_ / 64, H_, B_), 256, 0, stream>>>(qkv, val_out);

  sgemm_bias<<<dim3(C_ / 128, (B_ * T_) / 128), 256, 0, stream>>>(
      qkv + 2 * C_, Wproj, bproj, out, B_ * T_, C_, C_, TC3);
}

// Round 3
// 1187.464 us; speedup vs baseline: 1.7980x; 1.7980x over previous
//
#include <hip/hip_runtime.h>
#include <math.h>

// Problem constants (B,T,C,H) = (4, 2048, 1024, 16), D = 64.
#define B_   4
#define T_   2048
#define C_   1024
#define H_   16
#define D_   64
#define TC3  3072   // 3*C

typedef __attribute__((ext_vector_type(8))) short short8;
typedef __attribute__((ext_vector_type(8))) unsigned short ushortv8;
typedef __attribute__((ext_vector_type(4))) float f32x4;

__device__ __forceinline__ float bf2f(unsigned short u) {
  unsigned int x = ((unsigned int)u) << 16;
  float f; __builtin_memcpy(&f, &x, 4); return f;
}
__device__ __forceinline__ unsigned short f2bf(float f) {   // round-nearest-even
  unsigned int x; __builtin_memcpy(&x, &f, 4);
  x += 0x7fff + ((x >> 16) & 1);
  return (unsigned short)(x >> 16);
}

#define GLOAD_LDS(gp, lp) __builtin_amdgcn_global_load_lds( \
    (const __attribute__((address_space(1))) unsigned int*)(gp), \
    (__attribute__((address_space(3))) unsigned int*)(lp), 16, 0, 0)

// ---------------------------------------------------------------------------
// Transpose + fp32->bf16 convert: W[K][N] f32 -> WT[N][K] bf16. 64x64 tiles.
// ---------------------------------------------------------------------------
__global__ __launch_bounds__(256)
void transpose_bf16(const float* __restrict__ W, unsigned short* __restrict__ WT,
                    int K, int N) {
  __shared__ float tile[64][65];
  const int k0 = blockIdx.y * 64, n0 = blockIdx.x * 64;
  const int r = threadIdx.x >> 4, c4 = (threadIdx.x & 15) * 4;
#pragma unroll
  for (int p = 0; p < 4; ++p) {
    int kk = p * 16 + r;
    float4 v = *(const float4*)(W + (size_t)(k0 + kk) * N + n0 + c4);
    tile[kk][c4 + 0] = v.x; tile[kk][c4 + 1] = v.y;
    tile[kk][c4 + 2] = v.z; tile[kk][c4 + 3] = v.w;
  }
  __syncthreads();
#pragma unroll
  for (int p = 0; p < 4; ++p) {
    int nn = p * 16 + r;
    ushort4 o = { f2bf(tile[c4 + 0][nn]), f2bf(tile[c4 + 1][nn]),
                  f2bf(tile[c4 + 2][nn]), f2bf(tile[c4 + 3][nn]) };
    *(ushort4*)(WT + (size_t)(n0 + nn) * K + k0 + c4) = o;
  }
}

// ---------------------------------------------------------------------------
// bf16 MFMA GEMM: C[m][n] = A[m][:] . Bt[n][:] + bias[n]
//  - A: f32 (convert-in-staging) or bf16 (global_load_lds), leading dim lda.
//  - Bt: bf16, row n holds k-contiguous (pre-transposed weight), ldb.
//  - 128x128 tile, BK=64, 256 thr = 4 waves (2x2 of 64x64), 16x16x32 MFMA.
//  - LDS tiles [128 rows][64 k] bf16, XOR swizzle: phys_chunk = c ^ (row&7)
//    (16B chunks) -> conflict-free staged writes AND frag reads.
// ---------------------------------------------------------------------------
template<bool A_F32, bool OUT_BF16>
__global__ __launch_bounds__(256)
void gemm_mfma(const void* __restrict__ Av, const unsigned short* __restrict__ Bt,
               const float* __restrict__ bias, void* __restrict__ Cv,
               int K, int lda, int ldb, int ldc) {
  __shared__ unsigned short As[128 * 64];
  __shared__ unsigned short Bs[128 * 64];
  const int tid = threadIdx.x;
  const int l = tid & 63, w = tid >> 6;
  const int m0 = blockIdx.y * 128, n0 = blockIdx.x * 128;
  const int wm = (w & 1) * 64, wn = (w >> 1) * 64;
  const int fr = l & 15, g = l >> 4;

  f32x4 acc[4][4];
#pragma unroll
  for (int i = 0; i < 4; ++i)
#pragma unroll
    for (int j = 0; j < 4; ++j) acc[i][j] = (f32x4)0.f;

  const int ar = tid >> 3;          // f32-staging: row within 32-row slab
  const int ac = tid & 7;           // f32-staging: logical chunk
  const int gr = l >> 3;            // lds-direct: row within 8-row slab
  const int gc = (l & 7) ^ gr;      // lds-direct: logical chunk (pre-swizzled)

  for (int kt = 0; kt < K; kt += 64) {
    __syncthreads();
    if (A_F32) {
      const float* Af = (const float*)Av;
#pragma unroll
      for (int p = 0; p < 4; ++p) {
        int r = p * 32 + ar;
        const float* src = Af + (size_t)(m0 + r) * lda + kt + ac * 8;
        float4 f0 = *(const float4*)src;
        float4 f1 = *(const float4*)(src + 4);
        ushortv8 u = { f2bf(f0.x), f2bf(f0.y), f2bf(f0.z), f2bf(f0.w),
                       f2bf(f1.x), f2bf(f1.y), f2bf(f1.z), f2bf(f1.w) };
        *(ushortv8*)&As[r * 64 + ((ac ^ (r & 7)) << 3)] = u;
      }
    } else {
      const unsigned short* Ab = (const unsigned short*)Av;
#pragma unroll
      for (int q = 0; q < 4; ++q) {
        int rr = (w * 4 + q) * 8 + gr;
        GLOAD_LDS(Ab + (size_t)(m0 + rr) * lda + kt + gc * 8,
                  &As[(w * 4 + q) * 512]);
      }
    }
#pragma unroll
    for (int q = 0; q < 4; ++q) {
      int rr = (w * 4 + q) * 8 + gr;
      GLOAD_LDS(Bt + (size_t)(n0 + rr) * ldb + kt + gc * 8,
                &Bs[(w * 4 + q) * 512]);
    }
    __syncthreads();

#pragma unroll
    for (int s = 0; s < 2; ++s) {
      const int cofs = (((s * 4 + g) ^ (fr & 7)) << 3);
      short8 a[4], b[4];
#pragma unroll
      for (int i = 0; i < 4; ++i)
        a[i] = *(const short8*)&As[(wm + i * 16 + fr) * 64 + cofs];
#pragma unroll
      for (int j = 0; j < 4; ++j)
        b[j] = *(const short8*)&Bs[(wn + j * 16 + fr) * 64 + cofs];
#pragma unroll
      for (int i = 0; i < 4; ++i)
#pragma unroll
        for (int j = 0; j < 4; ++j)
          acc[i][j] = __builtin_amdgcn_mfma_f32_16x16x32_bf16(
              a[i], b[j], acc[i][j], 0, 0, 0);
    }
  }

  // epilogue: C/D layout col = lane&15, row = (lane>>4)*4 + reg  [m89/m91]
#pragma unroll
  for (int j = 0; j < 4; ++j) {
    const int n = n0 + wn + j * 16 + fr;
    const float bv = bias[n];
#pragma unroll
    for (int i = 0; i < 4; ++i) {
#pragma unroll
      for (int rg = 0; rg < 4; ++rg) {
        const int m = m0 + wm + i * 16 + g * 4 + rg;
        float v = acc[i][j][rg] + bv;
        if (OUT_BF16) ((unsigned short*)Cv)[(size_t)m * ldc + n] = f2bf(v);
        else          ((float*)Cv)[(size_t)m * ldc + n] = v;
      }
    }
  }
}

// ---------------------------------------------------------------------------
// Fused per-head RMSNorm + RoPE (in-place on bf16 q,k) + fp32 value output.
// One wave per (b,t,h); lane = d.
// ---------------------------------------------------------------------------
__global__ __launch_bounds__(256)
void rmsrope_kernel(unsigned short* __restrict__ qkv,
                    const float* __restrict__ lambp,
                    float* __restrict__ valOut) {
  const int unit = blockIdx.x * 4 + (threadIdx.x >> 6);
  const int lane = threadIdx.x & 63;
  const int b = unit / (T_ * H_);
  const int rem = unit % (T_ * H_);
  const int t = rem / H_;
  const int h = rem % H_;
  const size_t base = (size_t)(b * T_ + t) * TC3;
  const float lamb = lambp[0];

  const int i = lane & 31;
  const float inv = 1.0f / powf(10000.0f, (float)(2 * i) * (1.0f / 64.0f));
  const float ang = (float)t * inv;
  const float cs = cosf(ang);
  const float sn = sinf(ang);

  {
    const size_t idx = base + h * 64 + lane;
    float q = bf2f(qkv[idx]);
    float ss = q * q;
    ss += __shfl_xor(ss, 32); ss += __shfl_xor(ss, 16);
    ss += __shfl_xor(ss, 8);  ss += __shfl_xor(ss, 4);
    ss += __shfl_xor(ss, 2);  ss += __shfl_xor(ss, 1);
    float qn = q * (1.0f / sqrtf(ss * (1.0f / 64.0f) + 1e-6f));
    float part = __shfl_xor(qn, 32);
    float out = (lane < 32) ? (qn * cs + part * sn) : (qn * cs - part * sn);
    qkv[idx] = f2bf(out);
  }
  {
    const size_t idx = base + C_ + h * 64 + lane;
    float k = bf2f(qkv[idx]);
    float ss = k * k;
    ss += __shfl_xor(ss, 32); ss += __shfl_xor(ss, 16);
    ss += __shfl_xor(ss, 8);  ss += __shfl_xor(ss, 4);
    ss += __shfl_xor(ss, 2);  ss += __shfl_xor(ss, 1);
    float kn = k * (1.0f / sqrtf(ss * (1.0f / 64.0f) + 1e-6f));
    float part = __shfl_xor(kn, 32);
    float out = (lane < 32) ? (kn * cs + part * sn) : (kn * cs - part * sn);
    qkv[idx] = f2bf(out);
  }
  {
    float v = bf2f(qkv[base + 2 * C_ + h * 64 + lane]);
    float val = (1.0f - lamb) * v + lamb * v;
    valOut[(size_t)((b * H_ + h) * T_ + t) * D_ + lane] = val;
  }
}

// ---------------------------------------------------------------------------
// Flash-style causal attention, fp32 compute, bf16 Q/K input, fp32 V input.
// v3: R2 swizzle kept; register prefetch REMOVED (it spilled: 780 MB scratch
// writes in R2). Epilogue writes attn as bf16 into qkv's dead v-columns,
// which is GEMM2's A operand (lda = 3072 bf16 elements).
// ---------------------------------------------------------------------------
#define SW4(c4, rsh) (((c4) ^ ((rsh) & 7)) * 4)

__global__ __launch_bounds__(256)
void flash_kernel(unsigned short* __restrict__ qkv,
                  const float* __restrict__ vvals) {
  __shared__ __align__(16) float Qs[64 * 64];
  __shared__ __align__(16) float Ks[64 * 64];
  __shared__ __align__(16) float Vs[64 * 64];
  float* Ps = Ks;   // P^T overwrites K tile after S-compute

  const int qt = gridDim.x - 1 - blockIdx.x;   // heavy blocks first
  const int h  = blockIdx.y;
  const int b  = blockIdx.z;
  const int tid = threadIdx.x;
  const int ty = tid >> 4;
  const int tx = tid & 15;
  const int q0 = qt * 64;
  const int lrow = tid >> 4;
  const int lc4  = tid & 15;

  // Q tile -> LDS (bf16 -> f32, swizzled)
#pragma unroll
  for (int it = 0; it < 4; ++it) {
    int r = it * 16 + lrow;
    ushort4 raw = *(const ushort4*)(
        qkv + (size_t)(b * T_ + q0 + r) * TC3 + h * 64 + lc4 * 4);
    float4 qv = { bf2f(raw.x), bf2f(raw.y), bf2f(raw.z), bf2f(raw.w) };
    *(float4*)&Qs[r * 64 + SW4(lc4, r >> 2)] = qv;
  }

  float m_i[4], l_i[4], o[4][4];
#pragma unroll
  for (int ii = 0; ii < 4; ++ii) {
    m_i[ii] = -INFINITY; l_i[ii] = 0.f;
#pragma unroll
    for (int dd = 0; dd < 4; ++dd) o[ii][dd] = 0.f;
  }

  for (int kt = 0; kt <= qt; ++kt) {
    const int k0 = kt * 64;
    __syncthreads();   // previous Ps(=Ks)/Vs fully consumed
#pragma unroll
    for (int it = 0; it < 4; ++it) {
      int r = it * 16 + lrow;
      ushort4 raw = *(const ushort4*)(
          qkv + (size_t)(b * T_ + k0 + r) * TC3 + C_ + h * 64 + lc4 * 4);
      float4 kv = { bf2f(raw.x), bf2f(raw.y), bf2f(raw.z), bf2f(raw.w) };
      *(float4*)&Ks[r * 64 + SW4(lc4, r >> 2)] = kv;
      *(float4*)&Vs[r * 64 + SW4(lc4, r >> 2)] = *(const float4*)(
          vvals + (size_t)((b * H_ + h) * T_ + k0 + r) * D_ + lc4 * 4);
    }
    __syncthreads();

    float s[4][4];
#pragma unroll
    for (int ii = 0; ii < 4; ++ii)
#pragma unroll
      for (int jj = 0; jj < 4; ++jj) s[ii][jj] = 0.f;

#pragma unroll 4
    for (int d4 = 0; d4 < 16; ++d4) {
      const int qsl = SW4(d4, ty);
      const int ksl = SW4(d4, tx);
      float qa[4][4], ka[4][4];
#pragma unroll
      for (int ii = 0; ii < 4; ++ii) {
        float4 qv = *(const float4*)&Qs[(4 * ty + ii) * 64 + qsl];
        qa[ii][0] = qv.x; qa[ii][1] = qv.y; qa[ii][2] = qv.z; qa[ii][3] = qv.w;
      }
#pragma unroll
      for (int jj = 0; jj < 4; ++jj) {
        float4 kv = *(const float4*)&Ks[(4 * tx + jj) * 64 + ksl];
        ka[jj][0] = kv.x; ka[jj][1] = kv.y; ka[jj][2] = kv.z; ka[jj][3] = kv.w;
      }
#pragma unroll
      for (int ii = 0; ii < 4; ++ii)
#pragma unroll
        for (int jj = 0; jj < 4; ++jj)
#pragma unroll
          for (int c = 0; c < 4; ++c)
            s[ii][jj] = fmaf(qa[ii][c], ka[jj][c], s[ii][jj]);
    }

    const bool diag = (kt == qt);
#pragma unroll
    for (int ii = 0; ii < 4; ++ii)
#pragma unroll
      for (int jj = 0; jj < 4; ++jj) {
        float sv = s[ii][jj] * 0.125f;
        if (diag && (4 * tx + jj > 4 * ty + ii)) sv = -INFINITY;
        s[ii][jj] = sv;
      }

    __syncthreads();   // Ks consumed -> P^T may overwrite

    float p[4][4];
#pragma unroll
    for (int ii = 0; ii < 4; ++ii) {
      float rm = fmaxf(fmaxf(s[ii][0], s[ii][1]), fmaxf(s[ii][2], s[ii][3]));
      rm = fmaxf(rm, __shfl_xor(rm, 1));
      rm = fmaxf(rm, __shfl_xor(rm, 2));
      rm = fmaxf(rm, __shfl_xor(rm, 4));
      rm = fmaxf(rm, __shfl_xor(rm, 8));
      float mnew = fmaxf(m_i[ii], rm);
      float alpha = __expf(m_i[ii] - mnew);
      m_i[ii] = mnew;
      float rs = 0.f;
#pragma unroll
      for (int jj = 0; jj < 4; ++jj) {
        p[ii][jj] = __expf(s[ii][jj] - mnew);
        rs += p[ii][jj];
      }
      rs += __shfl_xor(rs, 1); rs += __shfl_xor(rs, 2);
      rs += __shfl_xor(rs, 4); rs += __shfl_xor(rs, 8);
      l_i[ii] = l_i[ii] * alpha + rs;
#pragma unroll
      for (int dd = 0; dd < 4; ++dd) o[ii][dd] *= alpha;
    }

#pragma unroll
    for (int jj = 0; jj < 4; ++jj) {
      float4 pv = {p[0][jj], p[1][jj], p[2][jj], p[3][jj]};
      *(float4*)&Ps[(4 * tx + jj) * 64 + SW4(ty, tx)] = pv;
    }
    __syncthreads();

#pragma unroll 4
    for (int j = 0; j < 64; ++j) {
      const int sl = (j >> 2) & 7;
      float4 pv4 = *(const float4*)&Ps[j * 64 + SW4(ty, sl)];
      float4 vv4 = *(const float4*)&Vs[j * 64 + SW4(tx, sl)];
      float pa[4] = {pv4.x, pv4.y, pv4.z, pv4.w};
      float va[4] = {vv4.x, vv4.y, vv4.z, vv4.w};
#pragma unroll
      for (int ii = 0; ii < 4; ++ii)
#pragma unroll
        for (int dd = 0; dd < 4; ++dd)
          o[ii][dd] = fmaf(pa[ii], va[dd], o[ii][dd]);
    }
  }

  // epilogue: bf16 attn into qkv v-columns (GEMM2's A operand)
#pragma unroll
  for (int ii = 0; ii < 4; ++ii) {
    float invl = 1.0f / l_i[ii];
    int row = q0 + 4 * ty + ii;
    ushort4 ov = { f2bf(o[ii][0] * invl), f2bf(o[ii][1] * invl),
                   f2bf(o[ii][2] * invl), f2bf(o[ii][3] * invl) };
    *(ushort4*)(qkv + (size_t)(b * T_ + row) * TC3 + 2 * C_ + h * 64 + 4 * tx) = ov;
  }
}

// ---------------------------------------------------------------------------
// Launch. d_in: x, Wqkv, bqkv, Wproj, bproj, lamb.
// d_out: out (B*T*C f32) then value (B*H*T*D f32).
// ws: qkvb bf16 (50.33 MB) | WqkvT bf16 (6.29 MB) | WprojT bf16 (2.10 MB).
// ---------------------------------------------------------------------------
extern "C" void kernel_launch(void* const* d_in, const int* in_sizes, int n_in,
                              void* d_out, int out_size, void* d_ws, size_t ws_size,
                              hipStream_t stream) {
  const float* x     = (const float*)d_in[0];
  const float* Wqkv  = (const float*)d_in[1];
  const float* bqkv  = (const float*)d_in[2];
  const float* Wproj = (const float*)d_in[3];
  const float* bproj = (const float*)d_in[4];
  const float* lamb  = (const float*)d_in[5];

  float* out     = (float*)d_out;
  float* val_out = out + (size_t)B_ * T_ * C_;

  unsigned short* qkvb   = (unsigned short*)d_ws;                 // B*T*3C bf16
  unsigned short* WqkvT  = qkvb + (size_t)B_ * T_ * TC3;          // 3C x C bf16
  unsigned short* WprojT = WqkvT + (size_t)TC3 * C_;              // C x C bf16

  // 0) weight transpose+convert
  transpose_bf16<<<dim3(TC3 / 64, C_ / 64), 256, 0, stream>>>(Wqkv, WqkvT, C_, TC3);
  transpose_bf16<<<dim3(C_ / 64, C_ / 64), 256, 0, stream>>>(Wproj, WprojT, C_, C_);

  // 1) qkv = x @ Wqkv + bqkv   (A f32, out bf16)
  gemm_mfma<true, true><<<dim3(TC3 / 128, (B_ * T_) / 128), 256, 0, stream>>>(
      x, WqkvT, bqkv, qkvb, C_, C_, C_, TC3);

  // 2) RMSNorm + RoPE in-place (bf16); value -> d_out (f32)
  rmsrope_kernel<<<dim3((B_ * T_ * H_) / 4), 256, 0, stream>>>(qkvb, lamb, val_out);

  // 3) causal flash attention; bf16 result into qkv v-columns
  flash_kernel<<<dim3(T_ / 64, H_, B_), 256, 0, stream>>>(qkvb, val_out);

  // 4) out = attn @ Wproj + bproj   (A bf16 lda=3072, out f32)
  gemm_mfma<false, false><<<dim3(C_ / 128, (B_ * T_) / 128), 256, 0, stream>>>(
      qkvb + 2 * C_, WprojT, bproj, out, C_, TC3, C_, C_);
}

// Round 4
// 520.120 us; speedup vs baseline: 4.1049x; 2.2831x over previous
//
#include <hip/hip_runtime.h>
#include <math.h>

// Problem constants (B,T,C,H) = (4, 2048, 1024, 16), D = 64.
#define B_   4
#define T_   2048
#define C_   1024
#define H_   16
#define D_   64
#define TC3  3072   // 3*C

typedef __attribute__((ext_vector_type(8))) short short8;
typedef __attribute__((ext_vector_type(8))) unsigned short ushortv8;
typedef __attribute__((ext_vector_type(4))) float f32x4;

__device__ __forceinline__ float bf2f(unsigned short u) {
  unsigned int x = ((unsigned int)u) << 16;
  float f; __builtin_memcpy(&f, &x, 4); return f;
}
__device__ __forceinline__ unsigned short f2bf(float f) {   // round-nearest-even
  unsigned int x; __builtin_memcpy(&x, &f, 4);
  x += 0x7fff + ((x >> 16) & 1);
  return (unsigned short)(x >> 16);
}

#define GLOAD_LDS(gp, lp) __builtin_amdgcn_global_load_lds( \
    (const __attribute__((address_space(1))) unsigned int*)(gp), \
    (__attribute__((address_space(3))) unsigned int*)(lp), 16, 0, 0)

// ---------------------------------------------------------------------------
// Transpose + fp32->bf16 convert: W[K][N] f32 -> WT[N][K] bf16. 64x64 tiles.
// ---------------------------------------------------------------------------
__global__ __launch_bounds__(256)
void transpose_bf16(const float* __restrict__ W, unsigned short* __restrict__ WT,
                    int K, int N) {
  __shared__ float tile[64][65];
  const int k0 = blockIdx.y * 64, n0 = blockIdx.x * 64;
  const int r = threadIdx.x >> 4, c4 = (threadIdx.x & 15) * 4;
#pragma unroll
  for (int p = 0; p < 4; ++p) {
    int kk = p * 16 + r;
    float4 v = *(const float4*)(W + (size_t)(k0 + kk) * N + n0 + c4);
    tile[kk][c4 + 0] = v.x; tile[kk][c4 + 1] = v.y;
    tile[kk][c4 + 2] = v.z; tile[kk][c4 + 3] = v.w;
  }
  __syncthreads();
#pragma unroll
  for (int p = 0; p < 4; ++p) {
    int nn = p * 16 + r;
    ushort4 o = { f2bf(tile[c4 + 0][nn]), f2bf(tile[c4 + 1][nn]),
                  f2bf(tile[c4 + 2][nn]), f2bf(tile[c4 + 3][nn]) };
    *(ushort4*)(WT + (size_t)(n0 + nn) * K + k0 + c4) = o;
  }
}

// ---------------------------------------------------------------------------
// bf16 MFMA GEMM (unchanged from R3 — validated).
// ---------------------------------------------------------------------------
template<bool A_F32, bool OUT_BF16>
__global__ __launch_bounds__(256)
void gemm_mfma(const void* __restrict__ Av, const unsigned short* __restrict__ Bt,
               const float* __restrict__ bias, void* __restrict__ Cv,
               int K, int lda, int ldb, int ldc) {
  __shared__ unsigned short As[128 * 64];
  __shared__ unsigned short Bs[128 * 64];
  const int tid = threadIdx.x;
  const int l = tid & 63, w = tid >> 6;
  const int m0 = blockIdx.y * 128, n0 = blockIdx.x * 128;
  const int wm = (w & 1) * 64, wn = (w >> 1) * 64;
  const int fr = l & 15, g = l >> 4;

  f32x4 acc[4][4];
#pragma unroll
  for (int i = 0; i < 4; ++i)
#pragma unroll
    for (int j = 0; j < 4; ++j) acc[i][j] = (f32x4)0.f;

  const int ar = tid >> 3;
  const int ac = tid & 7;
  const int gr = l >> 3;
  const int gc = (l & 7) ^ gr;

  for (int kt = 0; kt < K; kt += 64) {
    __syncthreads();
    if (A_F32) {
      const float* Af = (const float*)Av;
#pragma unroll
      for (int p = 0; p < 4; ++p) {
        int r = p * 32 + ar;
        const float* src = Af + (size_t)(m0 + r) * lda + kt + ac * 8;
        float4 f0 = *(const float4*)src;
        float4 f1 = *(const float4*)(src + 4);
        ushortv8 u = { f2bf(f0.x), f2bf(f0.y), f2bf(f0.z), f2bf(f0.w),
                       f2bf(f1.x), f2bf(f1.y), f2bf(f1.z), f2bf(f1.w) };
        *(ushortv8*)&As[r * 64 + ((ac ^ (r & 7)) << 3)] = u;
      }
    } else {
      const unsigned short* Ab = (const unsigned short*)Av;
#pragma unroll
      for (int q = 0; q < 4; ++q) {
        int rr = (w * 4 + q) * 8 + gr;
        GLOAD_LDS(Ab + (size_t)(m0 + rr) * lda + kt + gc * 8,
                  &As[(w * 4 + q) * 512]);
      }
    }
#pragma unroll
    for (int q = 0; q < 4; ++q) {
      int rr = (w * 4 + q) * 8 + gr;
      GLOAD_LDS(Bt + (size_t)(n0 + rr) * ldb + kt + gc * 8,
                &Bs[(w * 4 + q) * 512]);
    }
    __syncthreads();

#pragma unroll
    for (int s = 0; s < 2; ++s) {
      const int cofs = (((s * 4 + g) ^ (fr & 7)) << 3);
      short8 a[4], b[4];
#pragma unroll
      for (int i = 0; i < 4; ++i)
        a[i] = *(const short8*)&As[(wm + i * 16 + fr) * 64 + cofs];
#pragma unroll
      for (int j = 0; j < 4; ++j)
        b[j] = *(const short8*)&Bs[(wn + j * 16 + fr) * 64 + cofs];
#pragma unroll
      for (int i = 0; i < 4; ++i)
#pragma unroll
        for (int j = 0; j < 4; ++j)
          acc[i][j] = __builtin_amdgcn_mfma_f32_16x16x32_bf16(
              a[i], b[j], acc[i][j], 0, 0, 0);
    }
  }

#pragma unroll
  for (int j = 0; j < 4; ++j) {
    const int n = n0 + wn + j * 16 + fr;
    const float bv = bias[n];
#pragma unroll
    for (int i = 0; i < 4; ++i) {
#pragma unroll
      for (int rg = 0; rg < 4; ++rg) {
        const int m = m0 + wm + i * 16 + g * 4 + rg;
        float v = acc[i][j][rg] + bv;
        if (OUT_BF16) ((unsigned short*)Cv)[(size_t)m * ldc + n] = f2bf(v);
        else          ((float*)Cv)[(size_t)m * ldc + n] = v;
      }
    }
  }
}

// ---------------------------------------------------------------------------
// Fused per-head RMSNorm + RoPE (in-place on bf16 q,k) + fp32 value output.
// ---------------------------------------------------------------------------
__global__ __launch_bounds__(256)
void rmsrope_kernel(unsigned short* __restrict__ qkv,
                    const float* __restrict__ lambp,
                    float* __restrict__ valOut) {
  const int unit = blockIdx.x * 4 + (threadIdx.x >> 6);
  const int lane = threadIdx.x & 63;
  const int b = unit / (T_ * H_);
  const int rem = unit % (T_ * H_);
  const int t = rem / H_;
  const int h = rem % H_;
  const size_t base = (size_t)(b * T_ + t) * TC3;
  const float lamb = lambp[0];

  const int i = lane & 31;
  const float inv = 1.0f / powf(10000.0f, (float)(2 * i) * (1.0f / 64.0f));
  const float ang = (float)t * inv;
  const float cs = cosf(ang);
  const float sn = sinf(ang);

  {
    const size_t idx = base + h * 64 + lane;
    float q = bf2f(qkv[idx]);
    float ss = q * q;
    ss += __shfl_xor(ss, 32); ss += __shfl_xor(ss, 16);
    ss += __shfl_xor(ss, 8);  ss += __shfl_xor(ss, 4);
    ss += __shfl_xor(ss, 2);  ss += __shfl_xor(ss, 1);
    float qn = q * (1.0f / sqrtf(ss * (1.0f / 64.0f) + 1e-6f));
    float part = __shfl_xor(qn, 32);
    float out = (lane < 32) ? (qn * cs + part * sn) : (qn * cs - part * sn);
    qkv[idx] = f2bf(out);
  }
  {
    const size_t idx = base + C_ + h * 64 + lane;
    float k = bf2f(qkv[idx]);
    float ss = k * k;
    ss += __shfl_xor(ss, 32); ss += __shfl_xor(ss, 16);
    ss += __shfl_xor(ss, 8);  ss += __shfl_xor(ss, 4);
    ss += __shfl_xor(ss, 2);  ss += __shfl_xor(ss, 1);
    float kn = k * (1.0f / sqrtf(ss * (1.0f / 64.0f) + 1e-6f));
    float part = __shfl_xor(kn, 32);
    float out = (lane < 32) ? (kn * cs + part * sn) : (kn * cs - part * sn);
    qkv[idx] = f2bf(out);
  }
  {
    float v = bf2f(qkv[base + 2 * C_ + h * 64 + lane]);
    float val = (1.0f - lamb) * v + lamb * v;
    valOut[(size_t)((b * H_ + h) * T_ + t) * D_ + lane] = val;
  }
}

// ---------------------------------------------------------------------------
// V transpose: val (B,H,T,D) f32 -> vT (B,H,D,T) bf16. PV contraction is over
// key, so the V operand's MFMA B-fragment needs key-contiguous rows.
// ---------------------------------------------------------------------------
__global__ __launch_bounds__(256)
void vtrans_kernel(const float* __restrict__ val, unsigned short* __restrict__ vT) {
  __shared__ float tile[64][65];
  const int t0 = blockIdx.x * 64;
  const int head = blockIdx.y;             // b*H + h
  const int r = threadIdx.x >> 4, c4 = (threadIdx.x & 15) * 4;
#pragma unroll
  for (int p = 0; p < 4; ++p) {
    int tt = p * 16 + r;
    float4 v = *(const float4*)(val + ((size_t)head * T_ + t0 + tt) * D_ + c4);
    tile[tt][c4 + 0] = v.x; tile[tt][c4 + 1] = v.y;
    tile[tt][c4 + 2] = v.z; tile[tt][c4 + 3] = v.w;
  }
  __syncthreads();
#pragma unroll
  for (int p = 0; p < 4; ++p) {
    int d = p * 16 + r;
    ushort4 o = { f2bf(tile[c4 + 0][d]), f2bf(tile[c4 + 1][d]),
                  f2bf(tile[c4 + 2][d]), f2bf(tile[c4 + 3][d]) };
    *(ushort4*)(vT + ((size_t)head * D_ + d) * T_ + t0 + c4) = o;
  }
}

// ---------------------------------------------------------------------------
// MFMA flash attention (bf16 in / fp32 softmax+accum).
// Block: 256 thr = 4 waves, Q-tile 128 rows (wave w owns rows w*32..w*32+31 =
// 2 m-tiles), K-tile 64. 16x16x32 MFMA for S = Q.K^T and O += P.V.
// LDS (all bf16, 8-elem 16B chunks, phys chunk = c ^ (row&7)):
//   Qs 128x64 (16KB) | Ks 64x64 (8KB) | Vs=V^T 64x64 (8KB) | Ps 128x64 (16KB)
// Ps is wave-private (each wave writes/reads only its own 32 rows) -> 2
// barriers per K-iter. P hand-off per m120: C/D-layout -> LDS -> A-fragment.
// ---------------------------------------------------------------------------
__global__ __launch_bounds__(256)
void flash_mfma(unsigned short* __restrict__ qkv,
                const unsigned short* __restrict__ vT) {
  __shared__ unsigned short Qs[128 * 64];
  __shared__ unsigned short Ks[64 * 64];
  __shared__ unsigned short Vs[64 * 64];
  __shared__ unsigned short Ps[128 * 64];

  const int qt = gridDim.x - 1 - blockIdx.x;   // heavy blocks first
  const int h  = blockIdx.y;
  const int b  = blockIdx.z;
  const int tid = threadIdx.x;
  const int w = tid >> 6, l = tid & 63;
  const int fr = l & 15, quad = l >> 4;
  const int q0 = qt * 128;
  const int gr = l >> 3;              // row within 8-row slab
  const int gc = (l & 7) ^ gr;        // source chunk (pre-swizzled)
  const int f8 = fr & 7;

  // stage Q once (4 global_load_lds per wave; swizzle via source permute)
#pragma unroll
  for (int s = 0; s < 4; ++s) {
    int row = w * 32 + s * 8 + gr;
    GLOAD_LDS(qkv + (size_t)(b * T_ + q0 + row) * TC3 + h * 64 + gc * 8,
              &Qs[(w * 32 + s * 8) * 64]);
  }

  float m_st[2][4], l_st[2][4];
  f32x4 o[2][4];
#pragma unroll
  for (int i = 0; i < 2; ++i)
#pragma unroll
    for (int r = 0; r < 4; ++r) { m_st[i][r] = -INFINITY; l_st[i][r] = 0.f; }
#pragma unroll
  for (int i = 0; i < 2; ++i)
#pragma unroll
    for (int j = 0; j < 4; ++j) o[i][j] = (f32x4)0.f;

  const int nk = 2 * qt + 2;
  for (int kt = 0; kt < nk; ++kt) {
    const int k0 = kt * 64;
    __syncthreads();   // prev iter's Ks/Vs reads done (and Q staged, iter 0)
#pragma unroll
    for (int s = 0; s < 2; ++s) {
      int row = w * 16 + s * 8;
      GLOAD_LDS(qkv + (size_t)(b * T_ + k0 + row + gr) * TC3 + C_ + h * 64 + gc * 8,
                &Ks[row * 64]);
      GLOAD_LDS(vT + ((size_t)(b * H_ + h) * D_ + row + gr) * T_ + k0 + gc * 8,
                &Vs[row * 64]);
    }
    __syncthreads();

    // ---- S = Q K^T ----
    f32x4 sc[2][4];
#pragma unroll
    for (int i = 0; i < 2; ++i)
#pragma unroll
      for (int j = 0; j < 4; ++j) sc[i][j] = (f32x4)0.f;

#pragma unroll
    for (int kc = 0; kc < 2; ++kc) {
      const int cofs = (((kc * 4 + quad) ^ f8) << 3);
      short8 qf0 = *(const short8*)&Qs[(w * 32 + fr) * 64 + cofs];
      short8 qf1 = *(const short8*)&Qs[(w * 32 + 16 + fr) * 64 + cofs];
#pragma unroll
      for (int j = 0; j < 4; ++j) {
        short8 kf = *(const short8*)&Ks[(j * 16 + fr) * 64 + cofs];
        sc[0][j] = __builtin_amdgcn_mfma_f32_16x16x32_bf16(qf0, kf, sc[0][j], 0, 0, 0);
        sc[1][j] = __builtin_amdgcn_mfma_f32_16x16x32_bf16(qf1, kf, sc[1][j], 0, 0, 0);
      }
    }

    // ---- online softmax in C/D layout (row = quad*4+reg, col = fr) ----
#pragma unroll
    for (int i = 0; i < 2; ++i) {
      const int qmin = q0 + w * 32 + i * 16;
      const bool need = (k0 + 63 > qmin);
      const int qbase = qmin + quad * 4;
#pragma unroll
      for (int j = 0; j < 4; ++j) {
        const int keyg = k0 + j * 16 + fr;
#pragma unroll
        for (int r = 0; r < 4; ++r) {
          float sv = sc[i][j][r] * 0.125f;   // 1/sqrt(64)
          if (need && (keyg > qbase + r)) sv = -INFINITY;
          sc[i][j][r] = sv;
        }
      }
#pragma unroll
      for (int r = 0; r < 4; ++r) {
        float rm = fmaxf(fmaxf(sc[i][0][r], sc[i][1][r]),
                         fmaxf(sc[i][2][r], sc[i][3][r]));
        rm = fmaxf(rm, __shfl_xor(rm, 1));
        rm = fmaxf(rm, __shfl_xor(rm, 2));
        rm = fmaxf(rm, __shfl_xor(rm, 4));
        rm = fmaxf(rm, __shfl_xor(rm, 8));
        float mnew = fmaxf(m_st[i][r], rm);
        float alpha = __expf(m_st[i][r] - mnew);
        m_st[i][r] = mnew;
        float rs = 0.f;
#pragma unroll
        for (int j = 0; j < 4; ++j) {
          float pv = __expf(sc[i][j][r] - mnew);
          sc[i][j][r] = pv;            // sc now holds P
          rs += pv;
        }
        rs += __shfl_xor(rs, 1); rs += __shfl_xor(rs, 2);
        rs += __shfl_xor(rs, 4); rs += __shfl_xor(rs, 8);
        l_st[i][r] = l_st[i][r] * alpha + rs;
#pragma unroll
        for (int j = 0; j < 4; ++j) o[i][j][r] *= alpha;
      }
      // write P -> Ps (wave-private rows; swizzled; bf16)
      const int prow = w * 32 + i * 16 + quad * 4;
#pragma unroll
      for (int j = 0; j < 4; ++j) {
        const int key = j * 16 + fr;
#pragma unroll
        for (int r = 0; r < 4; ++r) {
          const int row = prow + r;
          Ps[row * 64 + (((key >> 3) ^ (row & 7)) << 3) + (key & 7)] =
              f2bf(sc[i][j][r]);
        }
      }
    }

    // ---- O += P V  (A-frag from Ps, B-frag from Vs=V^T) ----
#pragma unroll
    for (int kc = 0; kc < 2; ++kc) {
      const int cofs = (((kc * 4 + quad) ^ f8) << 3);
      short8 pf0 = *(const short8*)&Ps[(w * 32 + fr) * 64 + cofs];
      short8 pf1 = *(const short8*)&Ps[(w * 32 + 16 + fr) * 64 + cofs];
#pragma unroll
      for (int j = 0; j < 4; ++j) {
        short8 vf = *(const short8*)&Vs[(j * 16 + fr) * 64 + cofs];
        o[0][j] = __builtin_amdgcn_mfma_f32_16x16x32_bf16(pf0, vf, o[0][j], 0, 0, 0);
        o[1][j] = __builtin_amdgcn_mfma_f32_16x16x32_bf16(pf1, vf, o[1][j], 0, 0, 0);
      }
    }
  }

  // ---- epilogue: attn = O/l as bf16 into qkv's dead v-columns ----
#pragma unroll
  for (int i = 0; i < 2; ++i) {
    float invl[4];
#pragma unroll
    for (int r = 0; r < 4; ++r) invl[r] = 1.0f / l_st[i][r];
#pragma unroll
    for (int j = 0; j < 4; ++j) {
      const int d = j * 16 + fr;
#pragma unroll
      for (int r = 0; r < 4; ++r) {
        const int row = q0 + w * 32 + i * 16 + quad * 4 + r;
        qkv[(size_t)(b * T_ + row) * TC3 + 2 * C_ + h * 64 + d] =
            f2bf(o[i][j][r] * invl[r]);
      }
    }
  }
}

// ---------------------------------------------------------------------------
// Launch. d_in: x, Wqkv, bqkv, Wproj, bproj, lamb.
// d_out: out (B*T*C f32) then value (B*H*T*D f32).
// ws: qkvb bf16 (50.3MB) | WqkvT (6.3MB) | WprojT (2.1MB) | vT bf16 (16.8MB).
// ---------------------------------------------------------------------------
extern "C" void kernel_launch(void* const* d_in, const int* in_sizes, int n_in,
                              void* d_out, int out_size, void* d_ws, size_t ws_size,
                              hipStream_t stream) {
  const float* x     = (const float*)d_in[0];
  const float* Wqkv  = (const float*)d_in[1];
  const float* bqkv  = (const float*)d_in[2];
  const float* Wproj = (const float*)d_in[3];
  const float* bproj = (const float*)d_in[4];
  const float* lamb  = (const float*)d_in[5];

  float* out     = (float*)d_out;
  float* val_out = out + (size_t)B_ * T_ * C_;

  unsigned short* qkvb   = (unsigned short*)d_ws;                 // B*T*3C
  unsigned short* WqkvT  = qkvb + (size_t)B_ * T_ * TC3;          // 3C x C
  unsigned short* WprojT = WqkvT + (size_t)TC3 * C_;              // C x C
  unsigned short* vT     = WprojT + (size_t)C_ * C_;              // B*H*D*T

  transpose_bf16<<<dim3(TC3 / 64, C_ / 64), 256, 0, stream>>>(Wqkv, WqkvT, C_, TC3);
  transpose_bf16<<<dim3(C_ / 64, C_ / 64), 256, 0, stream>>>(Wproj, WprojT, C_, C_);

  gemm_mfma<true, true><<<dim3(TC3 / 128, (B_ * T_) / 128), 256, 0, stream>>>(
      x, WqkvT, bqkv, qkvb, C_, C_, C_, TC3);

  rmsrope_kernel<<<dim3((B_ * T_ * H_) / 4), 256, 0, stream>>>(qkvb, lamb, val_out);

  vtrans_kernel<<<dim3(T_ / 64, B_ * H_), 256, 0, stream>>>(val_out, vT);

  flash_mfma<<<dim3(T_ / 128, H_, B_), 256, 0, stream>>>(qkvb, vT);

  gemm_mfma<false, false><<<dim3(C_ / 128, (B_ * T_) / 128), 256, 0, stream>>>(
      qkvb + 2 * C_, WprojT, bproj, out, C_, TC3, C_, C_);
}

// Round 5
// 404.837 us; speedup vs baseline: 5.2739x; 1.2848x over previous
//
#include <hip/hip_runtime.h>
#include <math.h>

// Problem constants (B,T,C,H) = (4, 2048, 1024, 16), D = 64.
#define B_   4
#define T_   2048
#define C_   1024
#define H_   16
#define D_   64
#define TC3  3072   // 3*C

typedef __attribute__((ext_vector_type(8))) short short8;
typedef __attribute__((ext_vector_type(8))) unsigned short ushortv8;
typedef __attribute__((ext_vector_type(4))) float f32x4;

__device__ __forceinline__ float bf2f(unsigned short u) {
  unsigned int x = ((unsigned int)u) << 16;
  float f; __builtin_memcpy(&f, &x, 4); return f;
}
__device__ __forceinline__ unsigned short f2bf(float f) {   // round-nearest-even
  unsigned int x; __builtin_memcpy(&x, &f, 4);
  x += 0x7fff + ((x >> 16) & 1);
  return (unsigned short)(x >> 16);
}

#define GLOAD_LDS(gp, lp) __builtin_amdgcn_global_load_lds( \
    (const __attribute__((address_space(1))) unsigned int*)(gp), \
    (__attribute__((address_space(3))) unsigned int*)(lp), 16, 0, 0)

// ---------------------------------------------------------------------------
// Transpose + fp32->bf16 convert: W[K][N] f32 -> WT[N][K] bf16. 64x64 tiles.
// ---------------------------------------------------------------------------
__global__ __launch_bounds__(256)
void transpose_bf16(const float* __restrict__ W, unsigned short* __restrict__ WT,
                    int K, int N) {
  __shared__ float tile[64][65];
  const int k0 = blockIdx.y * 64, n0 = blockIdx.x * 64;
  const int r = threadIdx.x >> 4, c4 = (threadIdx.x & 15) * 4;
#pragma unroll
  for (int p = 0; p < 4; ++p) {
    int kk = p * 16 + r;
    float4 v = *(const float4*)(W + (size_t)(k0 + kk) * N + n0 + c4);
    tile[kk][c4 + 0] = v.x; tile[kk][c4 + 1] = v.y;
    tile[kk][c4 + 2] = v.z; tile[kk][c4 + 3] = v.w;
  }
  __syncthreads();
#pragma unroll
  for (int p = 0; p < 4; ++p) {
    int nn = p * 16 + r;
    ushort4 o = { f2bf(tile[c4 + 0][nn]), f2bf(tile[c4 + 1][nn]),
                  f2bf(tile[c4 + 2][nn]), f2bf(tile[c4 + 3][nn]) };
    *(ushort4*)(WT + (size_t)(n0 + nn) * K + k0 + c4) = o;
  }
}

// ---------------------------------------------------------------------------
// bf16 MFMA GEMM (unchanged — validated R3/R4).
// ---------------------------------------------------------------------------
template<bool A_F32, bool OUT_BF16>
__global__ __launch_bounds__(256)
void gemm_mfma(const void* __restrict__ Av, const unsigned short* __restrict__ Bt,
               const float* __restrict__ bias, void* __restrict__ Cv,
               int K, int lda, int ldb, int ldc) {
  __shared__ unsigned short As[128 * 64];
  __shared__ unsigned short Bs[128 * 64];
  const int tid = threadIdx.x;
  const int l = tid & 63, w = tid >> 6;
  const int m0 = blockIdx.y * 128, n0 = blockIdx.x * 128;
  const int wm = (w & 1) * 64, wn = (w >> 1) * 64;
  const int fr = l & 15, g = l >> 4;

  f32x4 acc[4][4];
#pragma unroll
  for (int i = 0; i < 4; ++i)
#pragma unroll
    for (int j = 0; j < 4; ++j) acc[i][j] = (f32x4)0.f;

  const int ar = tid >> 3;
  const int ac = tid & 7;
  const int gr = l >> 3;
  const int gc = (l & 7) ^ gr;

  for (int kt = 0; kt < K; kt += 64) {
    __syncthreads();
    if (A_F32) {
      const float* Af = (const float*)Av;
#pragma unroll
      for (int p = 0; p < 4; ++p) {
        int r = p * 32 + ar;
        const float* src = Af + (size_t)(m0 + r) * lda + kt + ac * 8;
        float4 f0 = *(const float4*)src;
        float4 f1 = *(const float4*)(src + 4);
        ushortv8 u = { f2bf(f0.x), f2bf(f0.y), f2bf(f0.z), f2bf(f0.w),
                       f2bf(f1.x), f2bf(f1.y), f2bf(f1.z), f2bf(f1.w) };
        *(ushortv8*)&As[r * 64 + ((ac ^ (r & 7)) << 3)] = u;
      }
    } else {
      const unsigned short* Ab = (const unsigned short*)Av;
#pragma unroll
      for (int q = 0; q < 4; ++q) {
        int rr = (w * 4 + q) * 8 + gr;
        GLOAD_LDS(Ab + (size_t)(m0 + rr) * lda + kt + gc * 8,
                  &As[(w * 4 + q) * 512]);
      }
    }
#pragma unroll
    for (int q = 0; q < 4; ++q) {
      int rr = (w * 4 + q) * 8 + gr;
      GLOAD_LDS(Bt + (size_t)(n0 + rr) * ldb + kt + gc * 8,
                &Bs[(w * 4 + q) * 512]);
    }
    __syncthreads();

#pragma unroll
    for (int s = 0; s < 2; ++s) {
      const int cofs = (((s * 4 + g) ^ (fr & 7)) << 3);
      short8 a[4], b[4];
#pragma unroll
      for (int i = 0; i < 4; ++i)
        a[i] = *(const short8*)&As[(wm + i * 16 + fr) * 64 + cofs];
#pragma unroll
      for (int j = 0; j < 4; ++j)
        b[j] = *(const short8*)&Bs[(wn + j * 16 + fr) * 64 + cofs];
#pragma unroll
      for (int i = 0; i < 4; ++i)
#pragma unroll
        for (int j = 0; j < 4; ++j)
          acc[i][j] = __builtin_amdgcn_mfma_f32_16x16x32_bf16(
              a[i], b[j], acc[i][j], 0, 0, 0);
    }
  }

#pragma unroll
  for (int j = 0; j < 4; ++j) {
    const int n = n0 + wn + j * 16 + fr;
    const float bv = bias[n];
#pragma unroll
    for (int i = 0; i < 4; ++i) {
#pragma unroll
      for (int rg = 0; rg < 4; ++rg) {
        const int m = m0 + wm + i * 16 + g * 4 + rg;
        float v = acc[i][j][rg] + bv;
        if (OUT_BF16) ((unsigned short*)Cv)[(size_t)m * ldc + n] = f2bf(v);
        else          ((float*)Cv)[(size_t)m * ldc + n] = v;
      }
    }
  }
}

// ---------------------------------------------------------------------------
// Fused per-head RMSNorm + RoPE (in-place on bf16 q,k) + fp32 value output.
// ---------------------------------------------------------------------------
__global__ __launch_bounds__(256)
void rmsrope_kernel(unsigned short* __restrict__ qkv,
                    const float* __restrict__ lambp,
                    float* __restrict__ valOut) {
  const int unit = blockIdx.x * 4 + (threadIdx.x >> 6);
  const int lane = threadIdx.x & 63;
  const int b = unit / (T_ * H_);
  const int rem = unit % (T_ * H_);
  const int t = rem / H_;
  const int h = rem % H_;
  const size_t base = (size_t)(b * T_ + t) * TC3;
  const float lamb = lambp[0];

  const int i = lane & 31;
  // 1/10000^(2i/64) = 2^(-log2(10000)*2i/64); log2(10000)=13.287712
  const float inv = __builtin_amdgcn_exp2f(-13.2877123795494f * (float)(2 * i)
                                           * (1.0f / 64.0f));
  const float ang = (float)t * inv;
  const float cs = cosf(ang);
  const float sn = sinf(ang);

  {
    const size_t idx = base + h * 64 + lane;
    float q = bf2f(qkv[idx]);
    float ss = q * q;
    ss += __shfl_xor(ss, 32); ss += __shfl_xor(ss, 16);
    ss += __shfl_xor(ss, 8);  ss += __shfl_xor(ss, 4);
    ss += __shfl_xor(ss, 2);  ss += __shfl_xor(ss, 1);
    float qn = q * (1.0f / sqrtf(ss * (1.0f / 64.0f) + 1e-6f));
    float part = __shfl_xor(qn, 32);
    float out = (lane < 32) ? (qn * cs + part * sn) : (qn * cs - part * sn);
    qkv[idx] = f2bf(out);
  }
  {
    const size_t idx = base + C_ + h * 64 + lane;
    float k = bf2f(qkv[idx]);
    float ss = k * k;
    ss += __shfl_xor(ss, 32); ss += __shfl_xor(ss, 16);
    ss += __shfl_xor(ss, 8);  ss += __shfl_xor(ss, 4);
    ss += __shfl_xor(ss, 2);  ss += __shfl_xor(ss, 1);
    float kn = k * (1.0f / sqrtf(ss * (1.0f / 64.0f) + 1e-6f));
    float part = __shfl_xor(kn, 32);
    float out = (lane < 32) ? (kn * cs + part * sn) : (kn * cs - part * sn);
    qkv[idx] = f2bf(out);
  }
  {
    float v = bf2f(qkv[base + 2 * C_ + h * 64 + lane]);
    float val = (1.0f - lamb) * v + lamb * v;
    valOut[(size_t)((b * H_ + h) * T_ + t) * D_ + lane] = val;
  }
}

// ---------------------------------------------------------------------------
// V transpose for the PV MFMA: reads bf16 v-columns of qkv (b,t)-major,
// applies the lamb transform, writes vT (B,H,D,T) bf16. Must run BEFORE
// flash_mfma (which overwrites the v-columns with attn output).
// ---------------------------------------------------------------------------
__global__ __launch_bounds__(256)
void vtrans_kernel(const unsigned short* __restrict__ qkv,
                   const float* __restrict__ lambp,
                   unsigned short* __restrict__ vT) {
  __shared__ float tile[64][65];
  const int t0 = blockIdx.x * 64;
  const int head = blockIdx.y;             // b*H + h
  const int b = head >> 4, h = head & 15;
  const float lamb = lambp[0];
  const int r = threadIdx.x >> 4, c4 = (threadIdx.x & 15) * 4;
#pragma unroll
  for (int p = 0; p < 4; ++p) {
    int tt = p * 16 + r;
    ushort4 raw = *(const ushort4*)(
        qkv + (size_t)(b * T_ + t0 + tt) * TC3 + 2 * C_ + h * 64 + c4);
    tile[tt][c4 + 0] = (1.f - lamb) * bf2f(raw.x) + lamb * bf2f(raw.x);
    tile[tt][c4 + 1] = (1.f - lamb) * bf2f(raw.y) + lamb * bf2f(raw.y);
    tile[tt][c4 + 2] = (1.f - lamb) * bf2f(raw.z) + lamb * bf2f(raw.z);
    tile[tt][c4 + 3] = (1.f - lamb) * bf2f(raw.w) + lamb * bf2f(raw.w);
  }
  __syncthreads();
#pragma unroll
  for (int p = 0; p < 4; ++p) {
    int d = p * 16 + r;
    ushort4 o = { f2bf(tile[c4 + 0][d]), f2bf(tile[c4 + 1][d]),
                  f2bf(tile[c4 + 2][d]), f2bf(tile[c4 + 3][d]) };
    *(ushort4*)(vT + ((size_t)head * D_ + d) * T_ + t0 + c4) = o;
  }
}

// ---------------------------------------------------------------------------
// MFMA flash attention — v2 (fixed-basis softmax).
// RMS-normed q,k => |s| <= 8, so exp(s) in [3.4e-4, 2981] and l <= 6e6: no
// overflow without max-subtraction. Changes vs R4:
//  * no running max / alpha / O-rescale; p = exp2(s * 0.125*log2e)
//  * l-reduction deferred to epilogue (per-lane partials in the loop) ->
//    ZERO cross-lane ops in the hot loop
//  * Q fragments hoisted out of the K-loop (iteration-invariant)
// Block: 4 waves, Q-tile 128 (wave = 32 rows), K-tile 64, 16x16x32 MFMA.
// LDS 48 KB (swizzle chunk = c ^ (row&7)); Ps wave-private -> 2 barriers/iter.
// ---------------------------------------------------------------------------
__global__ __launch_bounds__(256)
void flash_mfma(unsigned short* __restrict__ qkv,
                const unsigned short* __restrict__ vT) {
  __shared__ unsigned short Qs[128 * 64];
  __shared__ unsigned short Ks[64 * 64];
  __shared__ unsigned short Vs[64 * 64];
  __shared__ unsigned short Ps[128 * 64];

  const int qt = gridDim.x - 1 - blockIdx.x;   // heavy blocks first
  const int h  = blockIdx.y;
  const int b  = blockIdx.z;
  const int tid = threadIdx.x;
  const int w = tid >> 6, l = tid & 63;
  const int fr = l & 15, quad = l >> 4;
  const int q0 = qt * 128;
  const int gr = l >> 3;
  const int gc = (l & 7) ^ gr;
  const int f8 = fr & 7;

  // stage Q once
#pragma unroll
  for (int s = 0; s < 4; ++s) {
    int row = w * 32 + s * 8 + gr;
    GLOAD_LDS(qkv + (size_t)(b * T_ + q0 + row) * TC3 + h * 64 + gc * 8,
              &Qs[(w * 32 + s * 8) * 64]);
  }
  __syncthreads();   // Q staged (vmcnt drained by barrier semantics)

  // hoist iteration-invariant Q fragments
  short8 qf[2][2];
#pragma unroll
  for (int kc = 0; kc < 2; ++kc) {
    const int cofs = (((kc * 4 + quad) ^ f8) << 3);
    qf[kc][0] = *(const short8*)&Qs[(w * 32 + fr) * 64 + cofs];
    qf[kc][1] = *(const short8*)&Qs[(w * 32 + 16 + fr) * 64 + cofs];
  }

  float l_pt[2][4];
  f32x4 o[2][4];
#pragma unroll
  for (int i = 0; i < 2; ++i) {
#pragma unroll
    for (int r = 0; r < 4; ++r) l_pt[i][r] = 0.f;
#pragma unroll
    for (int j = 0; j < 4; ++j) o[i][j] = (f32x4)0.f;
  }

  const float SCL = 0.125f * 1.44269504088896f;   // scale * log2(e)
  const int nk = 2 * qt + 2;
  for (int kt = 0; kt < nk; ++kt) {
    const int k0 = kt * 64;
    __syncthreads();   // prev iter's Ks/Vs reads complete (WAR)
#pragma unroll
    for (int s = 0; s < 2; ++s) {
      int row = w * 16 + s * 8;
      GLOAD_LDS(qkv + (size_t)(b * T_ + k0 + row + gr) * TC3 + C_ + h * 64 + gc * 8,
                &Ks[row * 64]);
      GLOAD_LDS(vT + ((size_t)(b * H_ + h) * D_ + row + gr) * T_ + k0 + gc * 8,
                &Vs[row * 64]);
    }
    __syncthreads();

    // ---- S = Q K^T ----
    f32x4 sc[2][4];
#pragma unroll
    for (int i = 0; i < 2; ++i)
#pragma unroll
      for (int j = 0; j < 4; ++j) sc[i][j] = (f32x4)0.f;

#pragma unroll
    for (int kc = 0; kc < 2; ++kc) {
      const int cofs = (((kc * 4 + quad) ^ f8) << 3);
#pragma unroll
      for (int j = 0; j < 4; ++j) {
        short8 kf = *(const short8*)&Ks[(j * 16 + fr) * 64 + cofs];
        sc[0][j] = __builtin_amdgcn_mfma_f32_16x16x32_bf16(qf[kc][0], kf, sc[0][j], 0, 0, 0);
        sc[1][j] = __builtin_amdgcn_mfma_f32_16x16x32_bf16(qf[kc][1], kf, sc[1][j], 0, 0, 0);
      }
    }

    // ---- fixed-basis softmax: p = exp2(s*SCL), no max, deferred l ----
#pragma unroll
    for (int i = 0; i < 2; ++i) {
      const int qmin = q0 + w * 32 + i * 16;
      const bool need = (k0 + 63 > qmin);
      const int qbase = qmin + quad * 4;
      const int prow = w * 32 + i * 16 + quad * 4;
#pragma unroll
      for (int j = 0; j < 4; ++j) {
        const int keyg = k0 + j * 16 + fr;
#pragma unroll
        for (int r = 0; r < 4; ++r) {
          float arg = sc[i][j][r] * SCL;
          if (need && (keyg > qbase + r)) arg = -INFINITY;
          float p = __builtin_amdgcn_exp2f(arg);
          l_pt[i][r] += p;
          const int row = prow + r;
          Ps[row * 64 + ((((j * 16 + fr) >> 3) ^ (row & 7)) << 3) + f8] = f2bf(p);
        }
      }
    }

    // ---- O += P V  (A-frag from Ps [wave-private], B-frag from Vs=V^T) ----
#pragma unroll
    for (int kc = 0; kc < 2; ++kc) {
      const int cofs = (((kc * 4 + quad) ^ f8) << 3);
      short8 pf0 = *(const short8*)&Ps[(w * 32 + fr) * 64 + cofs];
      short8 pf1 = *(const short8*)&Ps[(w * 32 + 16 + fr) * 64 + cofs];
#pragma unroll
      for (int j = 0; j < 4; ++j) {
        short8 vf = *(const short8*)&Vs[(j * 16 + fr) * 64 + cofs];
        o[0][j] = __builtin_amdgcn_mfma_f32_16x16x32_bf16(pf0, vf, o[0][j], 0, 0, 0);
        o[1][j] = __builtin_amdgcn_mfma_f32_16x16x32_bf16(pf1, vf, o[1][j], 0, 0, 0);
      }
    }
  }

  // ---- epilogue: reduce l across the 16-lane col group, store O/l ----
#pragma unroll
  for (int i = 0; i < 2; ++i) {
    float invl[4];
#pragma unroll
    for (int r = 0; r < 4; ++r) {
      float lv = l_pt[i][r];
      lv += __shfl_xor(lv, 1); lv += __shfl_xor(lv, 2);
      lv += __shfl_xor(lv, 4); lv += __shfl_xor(lv, 8);
      invl[r] = 1.0f / lv;
    }
#pragma unroll
    for (int j = 0; j < 4; ++j) {
      const int d = j * 16 + fr;
#pragma unroll
      for (int r = 0; r < 4; ++r) {
        const int row = q0 + w * 32 + i * 16 + quad * 4 + r;
        qkv[(size_t)(b * T_ + row) * TC3 + 2 * C_ + h * 64 + d] =
            f2bf(o[i][j][r] * invl[r]);
      }
    }
  }
}

// ---------------------------------------------------------------------------
// Launch. d_in: x, Wqkv, bqkv, Wproj, bproj, lamb.
// d_out: out (B*T*C f32) then value (B*H*T*D f32).
// ws: qkvb bf16 (50.3MB) | WqkvT (6.3MB) | WprojT (2.1MB) | vT bf16 (16.8MB).
// ---------------------------------------------------------------------------
extern "C" void kernel_launch(void* const* d_in, const int* in_sizes, int n_in,
                              void* d_out, int out_size, void* d_ws, size_t ws_size,
                              hipStream_t stream) {
  const float* x     = (const float*)d_in[0];
  const float* Wqkv  = (const float*)d_in[1];
  const float* bqkv  = (const float*)d_in[2];
  const float* Wproj = (const float*)d_in[3];
  const float* bproj = (const float*)d_in[4];
  const float* lamb  = (const float*)d_in[5];

  float* out     = (float*)d_out;
  float* val_out = out + (size_t)B_ * T_ * C_;

  unsigned short* qkvb   = (unsigned short*)d_ws;                 // B*T*3C
  unsigned short* WqkvT  = qkvb + (size_t)B_ * T_ * TC3;          // 3C x C
  unsigned short* WprojT = WqkvT + (size_t)TC3 * C_;              // C x C
  unsigned short* vT     = WprojT + (size_t)C_ * C_;              // B*H*D*T

  transpose_bf16<<<dim3(TC3 / 64, C_ / 64), 256, 0, stream>>>(Wqkv, WqkvT, C_, TC3);
  transpose_bf16<<<dim3(C_ / 64, C_ / 64), 256, 0, stream>>>(Wproj, WprojT, C_, C_);

  gemm_mfma<true, true><<<dim3(TC3 / 128, (B_ * T_) / 128), 256, 0, stream>>>(
      x, WqkvT, bqkv, qkvb, C_, C_, C_, TC3);

  rmsrope_kernel<<<dim3((B_ * T_ * H_) / 4), 256, 0, stream>>>(qkvb, lamb, val_out);

  // vtrans BEFORE flash (flash overwrites qkv's v-columns with attn output)
  vtrans_kernel<<<dim3(T_ / 64, B_ * H_), 256, 0, stream>>>(qkvb, lamb, vT);

  flash_mfma<<<dim3(T_ / 128, H_, B_), 256, 0, stream>>>(qkvb, vT);

  gemm_mfma<false, false><<<dim3(C_ / 128, (B_ * T_) / 128), 256, 0, stream>>>(
      qkvb + 2 * C_, WprojT, bproj, out, C_, TC3, C_, C_);
}

// Round 6
// 373.667 us; speedup vs baseline: 5.7138x; 1.0834x over previous
//
#include <hip/hip_runtime.h>
#include <math.h>

// Problem constants (B,T,C,H) = (4, 2048, 1024, 16), D = 64.
#define B_   4
#define T_   2048
#define C_   1024
#define H_   16
#define D_   64
#define TC3  3072   // 3*C

typedef __attribute__((ext_vector_type(8))) short short8;
typedef __attribute__((ext_vector_type(4))) short short4b;
typedef __attribute__((ext_vector_type(8))) unsigned short ushortv8;
typedef __attribute__((ext_vector_type(4))) float f32x4;

__device__ __forceinline__ float bf2f(unsigned short u) {
  unsigned int x = ((unsigned int)u) << 16;
  float f; __builtin_memcpy(&f, &x, 4); return f;
}
__device__ __forceinline__ unsigned short f2bf(float f) {   // round-nearest-even
  unsigned int x; __builtin_memcpy(&x, &f, 4);
  x += 0x7fff + ((x >> 16) & 1);
  return (unsigned short)(x >> 16);
}

#define MFMA32(a, b, c) __builtin_amdgcn_mfma_f32_16x16x32_bf16(a, b, c, 0, 0, 0)
#if __has_builtin(__builtin_amdgcn_mfma_f32_16x16x16_bf16)
#define MFMA16(a, b, c) __builtin_amdgcn_mfma_f32_16x16x16_bf16(a, b, c, 0, 0, 0)
#else
#define MFMA16(a, b, c) __builtin_amdgcn_mfma_f32_16x16x16bf16_1k(a, b, c, 0, 0, 0)
#endif

#define GLOAD_LDS(gp, lp) __builtin_amdgcn_global_load_lds( \
    (const __attribute__((address_space(1))) unsigned int*)(gp), \
    (__attribute__((address_space(3))) unsigned int*)(lp), 16, 0, 0)

// ---------------------------------------------------------------------------
// x f32 -> bf16 (lets GEMM1 use the pure-bf16 global_load_lds staging path).
// ---------------------------------------------------------------------------
__global__ __launch_bounds__(256)
void convert_bf16(const float* __restrict__ x, unsigned short* __restrict__ xb) {
  const size_t i = ((size_t)blockIdx.x * 256 + threadIdx.x) * 8;
  float4 f0 = *(const float4*)(x + i);
  float4 f1 = *(const float4*)(x + i + 4);
  ushortv8 u = { f2bf(f0.x), f2bf(f0.y), f2bf(f0.z), f2bf(f0.w),
                 f2bf(f1.x), f2bf(f1.y), f2bf(f1.z), f2bf(f1.w) };
  *(ushortv8*)(xb + i) = u;
}

// ---------------------------------------------------------------------------
// Transpose + fp32->bf16 convert: W[K][N] f32 -> WT[N][K] bf16. 64x64 tiles.
// ---------------------------------------------------------------------------
__global__ __launch_bounds__(256)
void transpose_bf16(const float* __restrict__ W, unsigned short* __restrict__ WT,
                    int K, int N) {
  __shared__ float tile[64][65];
  const int k0 = blockIdx.y * 64, n0 = blockIdx.x * 64;
  const int r = threadIdx.x >> 4, c4 = (threadIdx.x & 15) * 4;
#pragma unroll
  for (int p = 0; p < 4; ++p) {
    int kk = p * 16 + r;
    float4 v = *(const float4*)(W + (size_t)(k0 + kk) * N + n0 + c4);
    tile[kk][c4 + 0] = v.x; tile[kk][c4 + 1] = v.y;
    tile[kk][c4 + 2] = v.z; tile[kk][c4 + 3] = v.w;
  }
  __syncthreads();
#pragma unroll
  for (int p = 0; p < 4; ++p) {
    int nn = p * 16 + r;
    ushort4 o = { f2bf(tile[c4 + 0][nn]), f2bf(tile[c4 + 1][nn]),
                  f2bf(tile[c4 + 2][nn]), f2bf(tile[c4 + 3][nn]) };
    *(ushort4*)(WT + (size_t)(n0 + nn) * K + k0 + c4) = o;
  }
}

// ---------------------------------------------------------------------------
// bf16 MFMA GEMM (validated R3-R5). A is always bf16 now (global_load_lds).
// ---------------------------------------------------------------------------
template<bool OUT_BF16>
__global__ __launch_bounds__(256)
void gemm_mfma(const unsigned short* __restrict__ Ab,
               const unsigned short* __restrict__ Bt,
               const float* __restrict__ bias, void* __restrict__ Cv,
               int K, int lda, int ldb, int ldc) {
  __shared__ unsigned short As[128 * 64];
  __shared__ unsigned short Bs[128 * 64];
  const int tid = threadIdx.x;
  const int l = tid & 63, w = tid >> 6;
  const int m0 = blockIdx.y * 128, n0 = blockIdx.x * 128;
  const int wm = (w & 1) * 64, wn = (w >> 1) * 64;
  const int fr = l & 15, g = l >> 4;

  f32x4 acc[4][4];
#pragma unroll
  for (int i = 0; i < 4; ++i)
#pragma unroll
    for (int j = 0; j < 4; ++j) acc[i][j] = (f32x4)0.f;

  const int gr = l >> 3;
  const int gc = (l & 7) ^ gr;

  for (int kt = 0; kt < K; kt += 64) {
    __syncthreads();
#pragma unroll
    for (int q = 0; q < 4; ++q) {
      int rr = (w * 4 + q) * 8 + gr;
      GLOAD_LDS(Ab + (size_t)(m0 + rr) * lda + kt + gc * 8,
                &As[(w * 4 + q) * 512]);
      GLOAD_LDS(Bt + (size_t)(n0 + rr) * ldb + kt + gc * 8,
                &Bs[(w * 4 + q) * 512]);
    }
    __syncthreads();

#pragma unroll
    for (int s = 0; s < 2; ++s) {
      const int cofs = (((s * 4 + g) ^ (fr & 7)) << 3);
      short8 a[4], b[4];
#pragma unroll
      for (int i = 0; i < 4; ++i)
        a[i] = *(const short8*)&As[(wm + i * 16 + fr) * 64 + cofs];
#pragma unroll
      for (int j = 0; j < 4; ++j)
        b[j] = *(const short8*)&Bs[(wn + j * 16 + fr) * 64 + cofs];
#pragma unroll
      for (int i = 0; i < 4; ++i)
#pragma unroll
        for (int j = 0; j < 4; ++j)
          acc[i][j] = MFMA32(a[i], b[j], acc[i][j]);
    }
  }

#pragma unroll
  for (int j = 0; j < 4; ++j) {
    const int n = n0 + wn + j * 16 + fr;
    const float bv = bias[n];
#pragma unroll
    for (int i = 0; i < 4; ++i) {
#pragma unroll
      for (int rg = 0; rg < 4; ++rg) {
        const int m = m0 + wm + i * 16 + g * 4 + rg;
        float v = acc[i][j][rg] + bv;
        if (OUT_BF16) ((unsigned short*)Cv)[(size_t)m * ldc + n] = f2bf(v);
        else          ((float*)Cv)[(size_t)m * ldc + n] = v;
      }
    }
  }
}

// ---------------------------------------------------------------------------
// Fused per-head RMSNorm + RoPE (in-place on bf16 q,k) + fp32 value output.
// ---------------------------------------------------------------------------
__global__ __launch_bounds__(256)
void rmsrope_kernel(unsigned short* __restrict__ qkv,
                    const float* __restrict__ lambp,
                    float* __restrict__ valOut) {
  const int unit = blockIdx.x * 4 + (threadIdx.x >> 6);
  const int lane = threadIdx.x & 63;
  const int b = unit / (T_ * H_);
  const int rem = unit % (T_ * H_);
  const int t = rem / H_;
  const int h = rem % H_;
  const size_t base = (size_t)(b * T_ + t) * TC3;
  const float lamb = lambp[0];

  const int i = lane & 31;
  const float inv = __builtin_amdgcn_exp2f(-13.2877123795494f * (float)(2 * i)
                                           * (1.0f / 64.0f));
  const float ang = (float)t * inv;
  const float cs = cosf(ang);
  const float sn = sinf(ang);

  {
    const size_t idx = base + h * 64 + lane;
    float q = bf2f(qkv[idx]);
    float ss = q * q;
    ss += __shfl_xor(ss, 32); ss += __shfl_xor(ss, 16);
    ss += __shfl_xor(ss, 8);  ss += __shfl_xor(ss, 4);
    ss += __shfl_xor(ss, 2);  ss += __shfl_xor(ss, 1);
    float qn = q * (1.0f / sqrtf(ss * (1.0f / 64.0f) + 1e-6f));
    float part = __shfl_xor(qn, 32);
    float out = (lane < 32) ? (qn * cs + part * sn) : (qn * cs - part * sn);
    qkv[idx] = f2bf(out);
  }
  {
    const size_t idx = base + C_ + h * 64 + lane;
    float k = bf2f(qkv[idx]);
    float ss = k * k;
    ss += __shfl_xor(ss, 32); ss += __shfl_xor(ss, 16);
    ss += __shfl_xor(ss, 8);  ss += __shfl_xor(ss, 4);
    ss += __shfl_xor(ss, 2);  ss += __shfl_xor(ss, 1);
    float kn = k * (1.0f / sqrtf(ss * (1.0f / 64.0f) + 1e-6f));
    float part = __shfl_xor(kn, 32);
    float out = (lane < 32) ? (kn * cs + part * sn) : (kn * cs - part * sn);
    qkv[idx] = f2bf(out);
  }
  {
    float v = bf2f(qkv[base + 2 * C_ + h * 64 + lane]);
    float val = (1.0f - lamb) * v + lamb * v;
    valOut[(size_t)((b * H_ + h) * T_ + t) * D_ + lane] = val;
  }
}

// ---------------------------------------------------------------------------
// V transpose: bf16 v-columns of qkv -> vT (B,H,D,T) bf16, with lamb applied.
// Runs BEFORE flash (flash overwrites v-columns with attn output).
// ---------------------------------------------------------------------------
__global__ __launch_bounds__(256)
void vtrans_kernel(const unsigned short* __restrict__ qkv,
                   const float* __restrict__ lambp,
                   unsigned short* __restrict__ vT) {
  __shared__ float tile[64][65];
  const int t0 = blockIdx.x * 64;
  const int head = blockIdx.y;             // b*H + h
  const int b = head >> 4, h = head & 15;
  const float lamb = lambp[0];
  const int r = threadIdx.x >> 4, c4 = (threadIdx.x & 15) * 4;
#pragma unroll
  for (int p = 0; p < 4; ++p) {
    int tt = p * 16 + r;
    ushort4 raw = *(const ushort4*)(
        qkv + (size_t)(b * T_ + t0 + tt) * TC3 + 2 * C_ + h * 64 + c4);
    tile[tt][c4 + 0] = (1.f - lamb) * bf2f(raw.x) + lamb * bf2f(raw.x);
    tile[tt][c4 + 1] = (1.f - lamb) * bf2f(raw.y) + lamb * bf2f(raw.y);
    tile[tt][c4 + 2] = (1.f - lamb) * bf2f(raw.z) + lamb * bf2f(raw.z);
    tile[tt][c4 + 3] = (1.f - lamb) * bf2f(raw.w) + lamb * bf2f(raw.w);
  }
  __syncthreads();
#pragma unroll
  for (int p = 0; p < 4; ++p) {
    int d = p * 16 + r;
    ushort4 o = { f2bf(tile[c4 + 0][d]), f2bf(tile[c4 + 1][d]),
                  f2bf(tile[c4 + 2][d]), f2bf(tile[c4 + 3][d]) };
    *(ushort4*)(vT + ((size_t)head * D_ + d) * T_ + t0 + c4) = o;
  }
}

// ---------------------------------------------------------------------------
// MFMA flash attention — v3 (register-resident P, no Ps LDS).
// S^T = K.Q^T via 16x16x32 MFMA (swapped operands): C/D col = q, row = key.
// That C/D layout IS the A-operand layout of v_mfma_f32_16x16x16_bf16
// (A[m=lane&15][k=quad*4+j]), so P = exp2(S^T*SCL) packs straight into the
// PV MFMA: O^T accum per d-tile with V^T rows as B-frag (b64 reads).
// l-partials are per-lane scalars (q = fr fixed per lane); reduced over
// quads in the epilogue. LDS: Qs 16KB + Ks 8KB + Vs 8KB = 32KB.
// ---------------------------------------------------------------------------
__global__ __launch_bounds__(256)
void flash_mfma(unsigned short* __restrict__ qkv,
                const unsigned short* __restrict__ vT) {
  __shared__ unsigned short Qs[128 * 64];
  __shared__ unsigned short Ks[64 * 64];
  __shared__ unsigned short Vs[64 * 64];

  const int qt = gridDim.x - 1 - blockIdx.x;   // heavy blocks first
  const int h  = blockIdx.y;
  const int b  = blockIdx.z;
  const int tid = threadIdx.x;
  const int w = tid >> 6, l = tid & 63;
  const int fr = l & 15, quad = l >> 4;
  const int q0 = qt * 128;
  const int gr = l >> 3;
  const int gc = (l & 7) ^ gr;
  const int f8 = fr & 7;

  // stage Q once
#pragma unroll
  for (int s = 0; s < 4; ++s) {
    int row = w * 32 + s * 8 + gr;
    GLOAD_LDS(qkv + (size_t)(b * T_ + q0 + row) * TC3 + h * 64 + gc * 8,
              &Qs[(w * 32 + s * 8) * 64]);
  }
  __syncthreads();

  // hoist iteration-invariant Q fragments (B-operand of S^T MFMA)
  short8 qf[2][2];
#pragma unroll
  for (int kc = 0; kc < 2; ++kc) {
    const int cofs = (((kc * 4 + quad) ^ f8) << 3);
    qf[kc][0] = *(const short8*)&Qs[(w * 32 + fr) * 64 + cofs];
    qf[kc][1] = *(const short8*)&Qs[(w * 32 + 16 + fr) * 64 + cofs];
  }

  float l_pt[2] = {0.f, 0.f};
  f32x4 o[2][4];
#pragma unroll
  for (int i = 0; i < 2; ++i)
#pragma unroll
    for (int j = 0; j < 4; ++j) o[i][j] = (f32x4)0.f;

  const float SCL = 0.125f * 1.44269504088896f;   // scale * log2(e)
  const int nk = 2 * qt + 2;
  for (int kt = 0; kt < nk; ++kt) {
    const int k0 = kt * 64;
    __syncthreads();   // prev iter's Ks/Vs reads complete (WAR)
#pragma unroll
    for (int s = 0; s < 2; ++s) {
      int row = w * 16 + s * 8;
      GLOAD_LDS(qkv + (size_t)(b * T_ + k0 + row + gr) * TC3 + C_ + h * 64 + gc * 8,
                &Ks[row * 64]);
      GLOAD_LDS(vT + ((size_t)(b * H_ + h) * D_ + row + gr) * T_ + k0 + gc * 8,
                &Vs[row * 64]);
    }
    __syncthreads();

    // ---- S^T = K Q^T : C/D col = q(fr), row = key(quad*4+reg) ----
    f32x4 st[2][4];
#pragma unroll
    for (int i = 0; i < 2; ++i)
#pragma unroll
      for (int j = 0; j < 4; ++j) st[i][j] = (f32x4)0.f;

#pragma unroll
    for (int kc = 0; kc < 2; ++kc) {
      const int cofs = (((kc * 4 + quad) ^ f8) << 3);
#pragma unroll
      for (int j = 0; j < 4; ++j) {
        short8 kf = *(const short8*)&Ks[(j * 16 + fr) * 64 + cofs];
        st[0][j] = MFMA32(kf, qf[kc][0], st[0][j]);
        st[1][j] = MFMA32(kf, qf[kc][1], st[1][j]);
      }
    }

    // ---- softmax (fixed basis, per-lane l) + pack P into A-frags ----
    short4b pa[2][4];
#pragma unroll
    for (int i = 0; i < 2; ++i) {
      const int qg = q0 + w * 32 + i * 16 + fr;
#pragma unroll
      for (int j = 0; j < 4; ++j) {
        const int kg = k0 + j * 16 + quad * 4;
#pragma unroll
        for (int r = 0; r < 4; ++r) {
          float arg = st[i][j][r] * SCL;
          if (kg + r > qg) arg = -INFINITY;   // branchless causal mask
          float p = __builtin_amdgcn_exp2f(arg);
          l_pt[i] += p;
          st[i][j][r] = p;
        }
        pa[i][j] = (short4b){ (short)f2bf(st[i][j][0]), (short)f2bf(st[i][j][1]),
                              (short)f2bf(st[i][j][2]), (short)f2bf(st[i][j][3]) };
      }
    }

    // ---- O^T += P V via 16x16x16 MFMA (P in regs, V^T b64 B-frags) ----
#pragma unroll
    for (int c = 0; c < 4; ++c) {
      const int vofs = ((((c * 2 + (quad >> 1)) ^ f8) << 3) + (quad & 1) * 4);
#pragma unroll
      for (int jd = 0; jd < 4; ++jd) {
        short4b vf = *(const short4b*)&Vs[(jd * 16 + fr) * 64 + vofs];
        o[0][jd] = MFMA16(pa[0][c], vf, o[0][jd]);
        o[1][jd] = MFMA16(pa[1][c], vf, o[1][jd]);
      }
    }
  }

  // ---- epilogue: reduce l over quads, store O/l (row=q via quad*4+r) ----
#pragma unroll
  for (int i = 0; i < 2; ++i) {
    float lv = l_pt[i];
    lv += __shfl_xor(lv, 16);
    lv += __shfl_xor(lv, 32);
    float inv = 1.0f / lv;
    float invq[4];
#pragma unroll
    for (int r = 0; r < 4; ++r) invq[r] = __shfl(inv, quad * 4 + r);
#pragma unroll
    for (int jd = 0; jd < 4; ++jd) {
      const int d = jd * 16 + fr;
#pragma unroll
      for (int r = 0; r < 4; ++r) {
        const int row = q0 + w * 32 + i * 16 + quad * 4 + r;
        qkv[(size_t)(b * T_ + row) * TC3 + 2 * C_ + h * 64 + d] =
            f2bf(o[i][jd][r] * invq[r]);
      }
    }
  }
}

// ---------------------------------------------------------------------------
// Launch. d_in: x, Wqkv, bqkv, Wproj, bproj, lamb.
// d_out: out (B*T*C f32) then value (B*H*T*D f32).
// ws: qkvb 50.3MB | WqkvT 6.3MB | WprojT 2.1MB | vT 16.8MB | xb 16.8MB.
// ---------------------------------------------------------------------------
extern "C" void kernel_launch(void* const* d_in, const int* in_sizes, int n_in,
                              void* d_out, int out_size, void* d_ws, size_t ws_size,
                              hipStream_t stream) {
  const float* x     = (const float*)d_in[0];
  const float* Wqkv  = (const float*)d_in[1];
  const float* bqkv  = (const float*)d_in[2];
  const float* Wproj = (const float*)d_in[3];
  const float* bproj = (const float*)d_in[4];
  const float* lamb  = (const float*)d_in[5];

  float* out     = (float*)d_out;
  float* val_out = out + (size_t)B_ * T_ * C_;

  unsigned short* qkvb   = (unsigned short*)d_ws;                 // B*T*3C
  unsigned short* WqkvT  = qkvb + (size_t)B_ * T_ * TC3;          // 3C x C
  unsigned short* WprojT = WqkvT + (size_t)TC3 * C_;              // C x C
  unsigned short* vT     = WprojT + (size_t)C_ * C_;              // B*H*D*T
  unsigned short* xb     = vT + (size_t)B_ * H_ * D_ * T_;        // B*T*C

  convert_bf16<<<dim3((B_ * T_ * C_) / 2048), 256, 0, stream>>>(x, xb);
  transpose_bf16<<<dim3(TC3 / 64, C_ / 64), 256, 0, stream>>>(Wqkv, WqkvT, C_, TC3);
  transpose_bf16<<<dim3(C_ / 64, C_ / 64), 256, 0, stream>>>(Wproj, WprojT, C_, C_);

  gemm_mfma<true><<<dim3(TC3 / 128, (B_ * T_) / 128), 256, 0, stream>>>(
      xb, WqkvT, bqkv, qkvb, C_, C_, C_, TC3);

  rmsrope_kernel<<<dim3((B_ * T_ * H_) / 4), 256, 0, stream>>>(qkvb, lamb, val_out);

  vtrans_kernel<<<dim3(T_ / 64, B_ * H_), 256, 0, stream>>>(qkvb, lamb, vT);

  flash_mfma<<<dim3(T_ / 128, H_, B_), 256, 0, stream>>>(qkvb, vT);

  gemm_mfma<false><<<dim3(C_ / 128, (B_ * T_) / 128), 256, 0, stream>>>(
      qkvb + 2 * C_, WprojT, bproj, out, C_, TC3, C_, C_);
}

// Round 7
// 327.275 us; speedup vs baseline: 6.5237x; 1.1418x over previous
//
#include <hip/hip_runtime.h>
#include <math.h>

// Problem constants (B,T,C,H) = (4, 2048, 1024, 16), D = 64.
#define B_   4
#define T_   2048
#define C_   1024
#define H_   16
#define D_   64
#define TC3  3072   // 3*C

typedef __attribute__((ext_vector_type(8))) short short8;
typedef __attribute__((ext_vector_type(4))) short short4b;
typedef __attribute__((ext_vector_type(8))) unsigned short ushortv8;
typedef __attribute__((ext_vector_type(4))) float f32x4;

__device__ __forceinline__ float bf2f(unsigned short u) {
  unsigned int x = ((unsigned int)u) << 16;
  float f; __builtin_memcpy(&f, &x, 4); return f;
}
__device__ __forceinline__ unsigned short f2bf(float f) {   // round-nearest-even
  unsigned int x; __builtin_memcpy(&x, &f, 4);
  x += 0x7fff + ((x >> 16) & 1);
  return (unsigned short)(x >> 16);
}

#define MFMA32(a, b, c) __builtin_amdgcn_mfma_f32_16x16x32_bf16(a, b, c, 0, 0, 0)
#if __has_builtin(__builtin_amdgcn_mfma_f32_16x16x16_bf16)
#define MFMA16(a, b, c) __builtin_amdgcn_mfma_f32_16x16x16_bf16(a, b, c, 0, 0, 0)
#else
#define MFMA16(a, b, c) __builtin_amdgcn_mfma_f32_16x16x16bf16_1k(a, b, c, 0, 0, 0)
#endif

#define GLOAD_LDS(gp, lp) __builtin_amdgcn_global_load_lds( \
    (const __attribute__((address_space(1))) unsigned int*)(gp), \
    (__attribute__((address_space(3))) unsigned int*)(lp), 16, 0, 0)

// ---------------------------------------------------------------------------
// x f32 -> bf16 (lets GEMM1 use the pure-bf16 global_load_lds staging path).
// ---------------------------------------------------------------------------
__global__ __launch_bounds__(256)
void convert_bf16(const float* __restrict__ x, unsigned short* __restrict__ xb) {
  const size_t i = ((size_t)blockIdx.x * 256 + threadIdx.x) * 8;
  float4 f0 = *(const float4*)(x + i);
  float4 f1 = *(const float4*)(x + i + 4);
  ushortv8 u = { f2bf(f0.x), f2bf(f0.y), f2bf(f0.z), f2bf(f0.w),
                 f2bf(f1.x), f2bf(f1.y), f2bf(f1.z), f2bf(f1.w) };
  *(ushortv8*)(xb + i) = u;
}

// ---------------------------------------------------------------------------
// Transpose + fp32->bf16 convert: W[K][N] f32 -> WT[N][K] bf16. 64x64 tiles.
// ---------------------------------------------------------------------------
__global__ __launch_bounds__(256)
void transpose_bf16(const float* __restrict__ W, unsigned short* __restrict__ WT,
                    int K, int N) {
  __shared__ float tile[64][65];
  const int k0 = blockIdx.y * 64, n0 = blockIdx.x * 64;
  const int r = threadIdx.x >> 4, c4 = (threadIdx.x & 15) * 4;
#pragma unroll
  for (int p = 0; p < 4; ++p) {
    int kk = p * 16 + r;
    float4 v = *(const float4*)(W + (size_t)(k0 + kk) * N + n0 + c4);
    tile[kk][c4 + 0] = v.x; tile[kk][c4 + 1] = v.y;
    tile[kk][c4 + 2] = v.z; tile[kk][c4 + 3] = v.w;
  }
  __syncthreads();
#pragma unroll
  for (int p = 0; p < 4; ++p) {
    int nn = p * 16 + r;
    ushort4 o = { f2bf(tile[c4 + 0][nn]), f2bf(tile[c4 + 1][nn]),
                  f2bf(tile[c4 + 2][nn]), f2bf(tile[c4 + 3][nn]) };
    *(ushort4*)(WT + (size_t)(n0 + nn) * K + k0 + c4) = o;
  }
}

// ---------------------------------------------------------------------------
// bf16 MFMA GEMM (validated R3-R6). A bf16 via global_load_lds.
// ---------------------------------------------------------------------------
template<bool OUT_BF16>
__global__ __launch_bounds__(256)
void gemm_mfma(const unsigned short* __restrict__ Ab,
               const unsigned short* __restrict__ Bt,
               const float* __restrict__ bias, void* __restrict__ Cv,
               int K, int lda, int ldb, int ldc) {
  __shared__ unsigned short As[128 * 64];
  __shared__ unsigned short Bs[128 * 64];
  const int tid = threadIdx.x;
  const int l = tid & 63, w = tid >> 6;
  const int m0 = blockIdx.y * 128, n0 = blockIdx.x * 128;
  const int wm = (w & 1) * 64, wn = (w >> 1) * 64;
  const int fr = l & 15, g = l >> 4;

  f32x4 acc[4][4];
#pragma unroll
  for (int i = 0; i < 4; ++i)
#pragma unroll
    for (int j = 0; j < 4; ++j) acc[i][j] = (f32x4)0.f;

  const int gr = l >> 3;
  const int gc = (l & 7) ^ gr;

  for (int kt = 0; kt < K; kt += 64) {
    __syncthreads();
#pragma unroll
    for (int q = 0; q < 4; ++q) {
      int rr = (w * 4 + q) * 8 + gr;
      GLOAD_LDS(Ab + (size_t)(m0 + rr) * lda + kt + gc * 8,
                &As[(w * 4 + q) * 512]);
      GLOAD_LDS(Bt + (size_t)(n0 + rr) * ldb + kt + gc * 8,
                &Bs[(w * 4 + q) * 512]);
    }
    __syncthreads();

#pragma unroll
    for (int s = 0; s < 2; ++s) {
      const int cofs = (((s * 4 + g) ^ (fr & 7)) << 3);
      short8 a[4], b[4];
#pragma unroll
      for (int i = 0; i < 4; ++i)
        a[i] = *(const short8*)&As[(wm + i * 16 + fr) * 64 + cofs];
#pragma unroll
      for (int j = 0; j < 4; ++j)
        b[j] = *(const short8*)&Bs[(wn + j * 16 + fr) * 64 + cofs];
#pragma unroll
      for (int i = 0; i < 4; ++i)
#pragma unroll
        for (int j = 0; j < 4; ++j)
          acc[i][j] = MFMA32(a[i], b[j], acc[i][j]);
    }
  }

#pragma unroll
  for (int j = 0; j < 4; ++j) {
    const int n = n0 + wn + j * 16 + fr;
    const float bv = bias[n];
#pragma unroll
    for (int i = 0; i < 4; ++i) {
#pragma unroll
      for (int rg = 0; rg < 4; ++rg) {
        const int m = m0 + wm + i * 16 + g * 4 + rg;
        float v = acc[i][j][rg] + bv;
        if (OUT_BF16) ((unsigned short*)Cv)[(size_t)m * ldc + n] = f2bf(v);
        else          ((float*)Cv)[(size_t)m * ldc + n] = v;
      }
    }
  }
}

// ---------------------------------------------------------------------------
// Fused per-head RMSNorm + RoPE (in-place on bf16 q,k) + fp32 value output.
// ---------------------------------------------------------------------------
__global__ __launch_bounds__(256)
void rmsrope_kernel(unsigned short* __restrict__ qkv,
                    const float* __restrict__ lambp,
                    float* __restrict__ valOut) {
  const int unit = blockIdx.x * 4 + (threadIdx.x >> 6);
  const int lane = threadIdx.x & 63;
  const int b = unit / (T_ * H_);
  const int rem = unit % (T_ * H_);
  const int t = rem / H_;
  const int h = rem % H_;
  const size_t base = (size_t)(b * T_ + t) * TC3;
  const float lamb = lambp[0];

  const int i = lane & 31;
  const float inv = __builtin_amdgcn_exp2f(-13.2877123795494f * (float)(2 * i)
                                           * (1.0f / 64.0f));
  const float ang = (float)t * inv;
  const float cs = cosf(ang);
  const float sn = sinf(ang);

  {
    const size_t idx = base + h * 64 + lane;
    float q = bf2f(qkv[idx]);
    float ss = q * q;
    ss += __shfl_xor(ss, 32); ss += __shfl_xor(ss, 16);
    ss += __shfl_xor(ss, 8);  ss += __shfl_xor(ss, 4);
    ss += __shfl_xor(ss, 2);  ss += __shfl_xor(ss, 1);
    float qn = q * (1.0f / sqrtf(ss * (1.0f / 64.0f) + 1e-6f));
    float part = __shfl_xor(qn, 32);
    float out = (lane < 32) ? (qn * cs + part * sn) : (qn * cs - part * sn);
    qkv[idx] = f2bf(out);
  }
  {
    const size_t idx = base + C_ + h * 64 + lane;
    float k = bf2f(qkv[idx]);
    float ss = k * k;
    ss += __shfl_xor(ss, 32); ss += __shfl_xor(ss, 16);
    ss += __shfl_xor(ss, 8);  ss += __shfl_xor(ss, 4);
    ss += __shfl_xor(ss, 2);  ss += __shfl_xor(ss, 1);
    float kn = k * (1.0f / sqrtf(ss * (1.0f / 64.0f) + 1e-6f));
    float part = __shfl_xor(kn, 32);
    float out = (lane < 32) ? (kn * cs + part * sn) : (kn * cs - part * sn);
    qkv[idx] = f2bf(out);
  }
  {
    float v = bf2f(qkv[base + 2 * C_ + h * 64 + lane]);
    float val = (1.0f - lamb) * v + lamb * v;
    valOut[(size_t)((b * H_ + h) * T_ + t) * D_ + lane] = val;
  }
}

// ---------------------------------------------------------------------------
// V transpose: bf16 v-columns of qkv -> vT (B,H,D,T) bf16, with lamb applied.
// Runs BEFORE flash (flash overwrites v-columns with attn output).
// ---------------------------------------------------------------------------
__global__ __launch_bounds__(256)
void vtrans_kernel(const unsigned short* __restrict__ qkv,
                   const float* __restrict__ lambp,
                   unsigned short* __restrict__ vT) {
  __shared__ float tile[64][65];
  const int t0 = blockIdx.x * 64;
  const int head = blockIdx.y;             // b*H + h
  const int b = head >> 4, h = head & 15;
  const float lamb = lambp[0];
  const int r = threadIdx.x >> 4, c4 = (threadIdx.x & 15) * 4;
#pragma unroll
  for (int p = 0; p < 4; ++p) {
    int tt = p * 16 + r;
    ushort4 raw = *(const ushort4*)(
        qkv + (size_t)(b * T_ + t0 + tt) * TC3 + 2 * C_ + h * 64 + c4);
    tile[tt][c4 + 0] = (1.f - lamb) * bf2f(raw.x) + lamb * bf2f(raw.x);
    tile[tt][c4 + 1] = (1.f - lamb) * bf2f(raw.y) + lamb * bf2f(raw.y);
    tile[tt][c4 + 2] = (1.f - lamb) * bf2f(raw.z) + lamb * bf2f(raw.z);
    tile[tt][c4 + 3] = (1.f - lamb) * bf2f(raw.w) + lamb * bf2f(raw.w);
  }
  __syncthreads();
#pragma unroll
  for (int p = 0; p < 4; ++p) {
    int d = p * 16 + r;
    ushort4 o = { f2bf(tile[c4 + 0][d]), f2bf(tile[c4 + 1][d]),
                  f2bf(tile[c4 + 2][d]), f2bf(tile[c4 + 3][d]) };
    *(ushort4*)(vT + ((size_t)head * D_ + d) * T_ + t0 + c4) = o;
  }
}

// ---------------------------------------------------------------------------
// MFMA flash attention — v4 (balanced qt dispatch).
// R6 post-mortem: grid linear id = x + 16y + 256z and round-robin dispatch
// gives each CU 4 blocks with the SAME x => same qt => same work (prop. to
// qt+1): the qt=15 CU does 128 block-iters while the qt=0 CU does 8 and
// idles -> 13.8% occupancy, ~2x critical-path stretch. Fix: complementary
// qt pairing across z: qts {x, 15-x, (x+8)&15, 15-((x+8)&15)} sum to a
// CONSTANT 68 block-iters for every x (and stay bijections per z, so
// coverage of (qt, b) is exact). Also desynchronizes barrier phases.
// Everything else identical to R6 (register-resident P, fixed-basis softmax).
// ---------------------------------------------------------------------------
__global__ __launch_bounds__(256)
void flash_mfma(unsigned short* __restrict__ qkv,
                const unsigned short* __restrict__ vT) {
  __shared__ unsigned short Qs[128 * 64];
  __shared__ unsigned short Ks[64 * 64];
  __shared__ unsigned short Vs[64 * 64];

  // balanced work mapping: see header comment
  const int z = blockIdx.z;
  const int xx = ((int)blockIdx.x + ((z >> 1) << 3)) & 15;
  const int qt = (z & 1) ? (15 - xx) : xx;
  const int b  = z;
  const int h  = blockIdx.y;

  const int tid = threadIdx.x;
  const int w = tid >> 6, l = tid & 63;
  const int fr = l & 15, quad = l >> 4;
  const int q0 = qt * 128;
  const int gr = l >> 3;
  const int gc = (l & 7) ^ gr;
  const int f8 = fr & 7;

  // stage Q once
#pragma unroll
  for (int s = 0; s < 4; ++s) {
    int row = w * 32 + s * 8 + gr;
    GLOAD_LDS(qkv + (size_t)(b * T_ + q0 + row) * TC3 + h * 64 + gc * 8,
              &Qs[(w * 32 + s * 8) * 64]);
  }
  __syncthreads();

  // hoist iteration-invariant Q fragments (B-operand of S^T MFMA)
  short8 qf[2][2];
#pragma unroll
  for (int kc = 0; kc < 2; ++kc) {
    const int cofs = (((kc * 4 + quad) ^ f8) << 3);
    qf[kc][0] = *(const short8*)&Qs[(w * 32 + fr) * 64 + cofs];
    qf[kc][1] = *(const short8*)&Qs[(w * 32 + 16 + fr) * 64 + cofs];
  }

  float l_pt[2] = {0.f, 0.f};
  f32x4 o[2][4];
#pragma unroll
  for (int i = 0; i < 2; ++i)
#pragma unroll
    for (int j = 0; j < 4; ++j) o[i][j] = (f32x4)0.f;

  const float SCL = 0.125f * 1.44269504088896f;   // scale * log2(e)
  const int nk = 2 * qt + 2;
  for (int kt = 0; kt < nk; ++kt) {
    const int k0 = kt * 64;
    __syncthreads();   // prev iter's Ks/Vs reads complete (WAR)
#pragma unroll
    for (int s = 0; s < 2; ++s) {
      int row = w * 16 + s * 8;
      GLOAD_LDS(qkv + (size_t)(b * T_ + k0 + row + gr) * TC3 + C_ + h * 64 + gc * 8,
                &Ks[row * 64]);
      GLOAD_LDS(vT + ((size_t)(b * H_ + h) * D_ + row + gr) * T_ + k0 + gc * 8,
                &Vs[row * 64]);
    }
    __syncthreads();

    // ---- S^T = K Q^T : C/D col = q(fr), row = key(quad*4+reg) ----
    f32x4 st[2][4];
#pragma unroll
    for (int i = 0; i < 2; ++i)
#pragma unroll
      for (int j = 0; j < 4; ++j) st[i][j] = (f32x4)0.f;

#pragma unroll
    for (int kc = 0; kc < 2; ++kc) {
      const int cofs = (((kc * 4 + quad) ^ f8) << 3);
#pragma unroll
      for (int j = 0; j < 4; ++j) {
        short8 kf = *(const short8*)&Ks[(j * 16 + fr) * 64 + cofs];
        st[0][j] = MFMA32(kf, qf[kc][0], st[0][j]);
        st[1][j] = MFMA32(kf, qf[kc][1], st[1][j]);
      }
    }

    // ---- softmax (fixed basis, per-lane l) + pack P into A-frags ----
    short4b pa[2][4];
#pragma unroll
    for (int i = 0; i < 2; ++i) {
      const int qg = q0 + w * 32 + i * 16 + fr;
#pragma unroll
      for (int j = 0; j < 4; ++j) {
        const int kg = k0 + j * 16 + quad * 4;
#pragma unroll
        for (int r = 0; r < 4; ++r) {
          float arg = st[i][j][r] * SCL;
          if (kg + r > qg) arg = -INFINITY;   // branchless causal mask
          float p = __builtin_amdgcn_exp2f(arg);
          l_pt[i] += p;
          st[i][j][r] = p;
        }
        pa[i][j] = (short4b){ (short)f2bf(st[i][j][0]), (short)f2bf(st[i][j][1]),
                              (short)f2bf(st[i][j][2]), (short)f2bf(st[i][j][3]) };
      }
    }

    // ---- O^T += P V via 16x16x16 MFMA (P in regs, V^T b64 B-frags) ----
#pragma unroll
    for (int c = 0; c < 4; ++c) {
      const int vofs = ((((c * 2 + (quad >> 1)) ^ f8) << 3) + (quad & 1) * 4);
#pragma unroll
      for (int jd = 0; jd < 4; ++jd) {
        short4b vf = *(const short4b*)&Vs[(jd * 16 + fr) * 64 + vofs];
        o[0][jd] = MFMA16(pa[0][c], vf, o[0][jd]);
        o[1][jd] = MFMA16(pa[1][c], vf, o[1][jd]);
      }
    }
  }

  // ---- epilogue: reduce l over quads, store O/l (row=q via quad*4+r) ----
#pragma unroll
  for (int i = 0; i < 2; ++i) {
    float lv = l_pt[i];
    lv += __shfl_xor(lv, 16);
    lv += __shfl_xor(lv, 32);
    float inv = 1.0f / lv;
    float invq[4];
#pragma unroll
    for (int r = 0; r < 4; ++r) invq[r] = __shfl(inv, quad * 4 + r);
#pragma unroll
    for (int jd = 0; jd < 4; ++jd) {
      const int d = jd * 16 + fr;
#pragma unroll
      for (int r = 0; r < 4; ++r) {
        const int row = q0 + w * 32 + i * 16 + quad * 4 + r;
        qkv[(size_t)(b * T_ + row) * TC3 + 2 * C_ + h * 64 + d] =
            f2bf(o[i][jd][r] * invq[r]);
      }
    }
  }
}

// ---------------------------------------------------------------------------
// Launch. d_in: x, Wqkv, bqkv, Wproj, bproj, lamb.
// d_out: out (B*T*C f32) then value (B*H*T*D f32).
// ws: qkvb 50.3MB | WqkvT 6.3MB | WprojT 2.1MB | vT 16.8MB | xb 16.8MB.
// ---------------------------------------------------------------------------
extern "C" void kernel_launch(void* const* d_in, const int* in_sizes, int n_in,
                              void* d_out, int out_size, void* d_ws, size_t ws_size,
                              hipStream_t stream) {
  const float* x     = (const float*)d_in[0];
  const float* Wqkv  = (const float*)d_in[1];
  const float* bqkv  = (const float*)d_in[2];
  const float* Wproj = (const float*)d_in[3];
  const float* bproj = (const float*)d_in[4];
  const float* lamb  = (const float*)d_in[5];

  float* out     = (float*)d_out;
  float* val_out = out + (size_t)B_ * T_ * C_;

  unsigned short* qkvb   = (unsigned short*)d_ws;                 // B*T*3C
  unsigned short* WqkvT  = qkvb + (size_t)B_ * T_ * TC3;          // 3C x C
  unsigned short* WprojT = WqkvT + (size_t)TC3 * C_;              // C x C
  unsigned short* vT     = WprojT + (size_t)C_ * C_;              // B*H*D*T
  unsigned short* xb     = vT + (size_t)B_ * H_ * D_ * T_;        // B*T*C

  convert_bf16<<<dim3((B_ * T_ * C_) / 2048), 256, 0, stream>>>(x, xb);
  transpose_bf16<<<dim3(TC3 / 64, C_ / 64), 256, 0, stream>>>(Wqkv, WqkvT, C_, TC3);
  transpose_bf16<<<dim3(C_ / 64, C_ / 64), 256, 0, stream>>>(Wproj, WprojT, C_, C_);

  gemm_mfma<true><<<dim3(TC3 / 128, (B_ * T_) / 128), 256, 0, stream>>>(
      xb, WqkvT, bqkv, qkvb, C_, C_, C_, TC3);

  rmsrope_kernel<<<dim3((B_ * T_ * H_) / 4), 256, 0, stream>>>(qkvb, lamb, val_out);

  vtrans_kernel<<<dim3(T_ / 64, B_ * H_), 256, 0, stream>>>(qkvb, lamb, vT);

  flash_mfma<<<dim3(T_ / 128, H_, B_), 256, 0, stream>>>(qkvb, vT);

  gemm_mfma<false><<<dim3(C_ / 128, (B_ * T_) / 128), 256, 0, stream>>>(
      qkvb + 2 * C_, WprojT, bproj, out, C_, TC3, C_, C_);
}